// Round 1
// baseline (2201.513 us; speedup 1.0000x reference)
//
#include <hip/hip_runtime.h>
#include <math.h>

#define S_LEN 512
#define HID 2048
#define NH 16
#define NKV 4
#define HD 128
#define CL 8192
#define TAILN (CL - S_LEN)
#define INV_SQRT_HD 0.08838834764831845f

enum {
  SC_AMAX_X = 0, SC_AMAX_CK, SC_AMAX_CK_TAIL, SC_AMAX_CV, SC_AMAX_CV_TAIL,
  SC_AMAX_Q, SC_AMAX_K, SC_AMAX_V, SC_AMAX_AO, SC_MIN_L,
  SC_SCALE_X, SC_SCALE_CK, SC_SCALE_CV, SC_SCALE_Q, SC_SCALE_KNEW,
  SC_SCALE_VNEW, SC_SCALE_KOUT, SC_SCALE_VOUT, SC_SCALE_P, SC_SCALE_O,
  SC_NUM
};

__device__ __forceinline__ float warpMax64(float v) {
  #pragma unroll
  for (int o = 32; o; o >>= 1) v = fmaxf(v, __shfl_down(v, o, 64));
  return v;
}
__device__ __forceinline__ float warpMin64(float v) {
  #pragma unroll
  for (int o = 32; o; o >>= 1) v = fminf(v, __shfl_down(v, o, 64));
  return v;
}
// requires blockDim.x == 256
__device__ __forceinline__ float blockMax256(float v) {
  __shared__ float sm_[4];
  __syncthreads();
  v = warpMax64(v);
  if ((threadIdx.x & 63) == 0) sm_[threadIdx.x >> 6] = v;
  __syncthreads();
  return fmaxf(fmaxf(sm_[0], sm_[1]), fmaxf(sm_[2], sm_[3]));
}
__device__ __forceinline__ float blockMin256(float v) {
  __shared__ float sn_[4];
  __syncthreads();
  v = warpMin64(v);
  if ((threadIdx.x & 63) == 0) sn_[threadIdx.x >> 6] = v;
  __syncthreads();
  return fminf(fminf(sn_[0], sn_[1]), fminf(sn_[2], sn_[3]));
}
__device__ __forceinline__ void atomicMaxPosF(float* a, float v) {
  atomicMax((unsigned int*)a, __float_as_uint(v));
}
__device__ __forceinline__ void atomicMinPosF(float* a, float v) {
  atomicMin((unsigned int*)a, __float_as_uint(v));
}
__device__ __forceinline__ float clampq(float q) {
  return fminf(fmaxf(q, -128.f), 127.f);
}

__global__ void k_init(float* sc) {
  int i = threadIdx.x;
  if (i < SC_NUM) sc[i] = (i == SC_MIN_L) ? INFINITY : 0.f;
}

__global__ __launch_bounds__(256) void k_absmax4(const float* __restrict__ x, int n4, float* slot) {
  float m = 0.f;
  const float4* x4 = (const float4*)x;
  for (int i = blockIdx.x * 256 + threadIdx.x; i < n4; i += gridDim.x * 256) {
    float4 v = x4[i];
    m = fmaxf(m, fmaxf(fmaxf(fabsf(v.x), fabsf(v.y)), fmaxf(fabsf(v.z), fabsf(v.w))));
  }
  m = blockMax256(m);
  if (threadIdx.x == 0) atomicMaxPosF(slot, m);
}

__global__ __launch_bounds__(256) void k_absmax_cache(const float* __restrict__ x, float* sfull, float* stail) {
  float mf = 0.f, mt = 0.f;
  const float4* x4 = (const float4*)x;
  const int n4 = NKV * CL * HD / 4;
  for (int i = blockIdx.x * 256 + threadIdx.x; i < n4; i += gridDim.x * 256) {
    float4 v = x4[i];
    float a = fmaxf(fmaxf(fabsf(v.x), fabsf(v.y)), fmaxf(fabsf(v.z), fabsf(v.w)));
    mf = fmaxf(mf, a);
    int t = (i >> 5) & (CL - 1);   // HD/4 = 32 float4 per row
    if (t >= S_LEN) mt = fmaxf(mt, a);
  }
  mf = blockMax256(mf);
  mt = blockMax256(mt);
  if (threadIdx.x == 0) { atomicMaxPosF(sfull, mf); atomicMaxPosF(stail, mt); }
}

// per-out-channel weight fake-quant, one block per row
__global__ __launch_bounds__(256) void k_quant_w(const float* __restrict__ W, float* __restrict__ Wq, int K) {
  size_t base = (size_t)blockIdx.x * K;
  const float4* w4 = (const float4*)(W + base);
  float4* o4 = (float4*)(Wq + base);
  int n4 = K / 4;
  float am = 0.f;
  for (int i = threadIdx.x; i < n4; i += 256) {
    float4 v = w4[i];
    am = fmaxf(am, fmaxf(fmaxf(fabsf(v.x), fabsf(v.y)), fmaxf(fabsf(v.z), fabsf(v.w))));
  }
  am = blockMax256(am);
  float s = fmaxf(am, 1e-8f) / 127.f;
  for (int i = threadIdx.x; i < n4; i += 256) {
    float4 v = w4[i];
    v.x = clampq(rintf(v.x / s)) * s;
    v.y = clampq(rintf(v.y / s)) * s;
    v.z = clampq(rintf(v.z / s)) * s;
    v.w = clampq(rintf(v.w / s)) * s;
    o4[i] = v;
  }
}

__global__ __launch_bounds__(256) void k_quant_buf(const float* __restrict__ in, float* __restrict__ outp,
                                                   int n4, const float* __restrict__ sc, int slot) {
  float s = sc[slot];
  const float4* i4 = (const float4*)in;
  float4* o4 = (float4*)outp;
  for (int i = blockIdx.x * 256 + threadIdx.x; i < n4; i += gridDim.x * 256) {
    float4 v = i4[i];
    v.x = clampq(rintf(v.x / s)) * s;
    v.y = clampq(rintf(v.y / s)) * s;
    v.z = clampq(rintf(v.z / s)) * s;
    v.w = clampq(rintf(v.w / s)) * s;
    o4[i] = v;
  }
}

__global__ void k_combine1(float* sc) {
  sc[SC_SCALE_X]  = fmaxf(sc[SC_AMAX_X],  1e-8f) / 127.f;
  sc[SC_SCALE_CK] = fmaxf(sc[SC_AMAX_CK], 1e-8f) / 127.f;
  sc[SC_SCALE_CV] = fmaxf(sc[SC_AMAX_CV], 1e-8f) / 127.f;
}
__global__ void k_combine2(float* sc) {
  float sck = sc[SC_SCALE_CK], scv = sc[SC_SCALE_CV];
  float tqk = fminf(rintf(sc[SC_AMAX_CK_TAIL] / sck), 127.f) * sck;
  float tqv = fminf(rintf(sc[SC_AMAX_CV_TAIL] / scv), 127.f) * scv;
  sc[SC_SCALE_Q]    = fmaxf(sc[SC_AMAX_Q], 1e-8f) / 127.f;
  sc[SC_SCALE_KOUT] = fmaxf(sc[SC_AMAX_K], 1e-8f) / 127.f;
  sc[SC_SCALE_VOUT] = fmaxf(sc[SC_AMAX_V], 1e-8f) / 127.f;
  sc[SC_SCALE_KNEW] = fmaxf(fmaxf(tqk, sc[SC_AMAX_K]), 1e-8f) / 127.f;
  sc[SC_SCALE_VNEW] = fmaxf(fmaxf(tqv, sc[SC_AMAX_V]), 1e-8f) / 127.f;
}
__global__ void k_combine3(float* sc) {
  float amax_p = 1.0f / sc[SC_MIN_L];
  sc[SC_SCALE_P] = fmaxf(amax_p, 1e-8f) / 127.f;
}
__global__ void k_combine4(float* sc) {
  sc[SC_SCALE_O] = fmaxf(sc[SC_AMAX_AO], 1e-8f) / 127.f;
}

// C[M,N] = A[M,K] * B[N,K]^T + bias ; 64x64 tile, 4x4 per thread
__global__ __launch_bounds__(256) void k_gemm(const float* __restrict__ A, const float* __restrict__ B,
                                              const float* __restrict__ bias, float* __restrict__ C,
                                              int M, int N, int K) {
  __shared__ float As[64][17];
  __shared__ float Bs[64][17];
  int row0 = blockIdx.y * 64, col0 = blockIdx.x * 64;
  int tid = threadIdx.x;
  int lr = tid >> 2, lc = (tid & 3) << 2;
  int ty = tid >> 4, tx = tid & 15;
  float acc[4][4] = {};
  for (int k0 = 0; k0 < K; k0 += 16) {
    __syncthreads();
    float4 a = *(const float4*)&A[(size_t)(row0 + lr) * K + k0 + lc];
    float4 b = *(const float4*)&B[(size_t)(col0 + lr) * K + k0 + lc];
    As[lr][lc] = a.x; As[lr][lc + 1] = a.y; As[lr][lc + 2] = a.z; As[lr][lc + 3] = a.w;
    Bs[lr][lc] = b.x; Bs[lr][lc + 1] = b.y; Bs[lr][lc + 2] = b.z; Bs[lr][lc + 3] = b.w;
    __syncthreads();
    #pragma unroll
    for (int kk = 0; kk < 16; ++kk) {
      float av[4], bv[4];
      #pragma unroll
      for (int i = 0; i < 4; i++) av[i] = As[ty * 4 + i][kk];
      #pragma unroll
      for (int j = 0; j < 4; j++) bv[j] = Bs[tx * 4 + j][kk];
      #pragma unroll
      for (int i = 0; i < 4; i++)
        #pragma unroll
        for (int j = 0; j < 4; j++)
          acc[i][j] = fmaf(av[i], bv[j], acc[i][j]);
    }
  }
  #pragma unroll
  for (int i = 0; i < 4; i++) {
    size_t crow = (size_t)(row0 + ty * 4 + i) * N;
    #pragma unroll
    for (int j = 0; j < 4; j++) {
      int col = col0 + tx * 4 + j;
      C[crow + col] = acc[i][j] + (bias ? bias[col] : 0.f);
    }
  }
}

// in-place RoPE on [S, nheads*HD] + amax reduction; one thread per (s,h,d<64) pair
__global__ __launch_bounds__(256) void k_rope(float* __restrict__ B, const float* __restrict__ cosb,
                                              const float* __restrict__ sinb, int nheads,
                                              float* __restrict__ amax_slot) {
  int n = S_LEN * nheads * 64;
  int stride = nheads * HD;
  float am = 0.f;
  for (int idx = blockIdx.x * 256 + threadIdx.x; idx < n; idx += gridDim.x * 256) {
    int s = idx / (nheads * 64);
    int rem = idx - s * nheads * 64;
    int h = rem >> 6, d = rem & 63;
    float c1 = cosb[s * HD + d], s1 = sinb[s * HD + d];
    float c2 = cosb[s * HD + d + 64], s2 = sinb[s * HD + d + 64];
    float* p = &B[(size_t)s * stride + h * HD + d];
    float x1 = p[0], x2 = p[64];
    float y1 = x1 * c1 - x2 * s1;
    float y2 = x2 * c2 + x1 * s2;
    p[0] = y1; p[64] = y2;
    am = fmaxf(am, fmaxf(fabsf(y1), fabsf(y2)));
  }
  am = blockMax256(am);
  if (threadIdx.x == 0) atomicMaxPosF(amax_slot, am);
}

// write k_out / v_out (fq of fresh k,v) into d_out after the main output
__global__ __launch_bounds__(256) void k_kvout(const float* __restrict__ KB, const float* __restrict__ VB,
                                               float* __restrict__ dout, const float* __restrict__ sc) {
  const int n1 = NKV * S_LEN * HD;
  float sk = sc[SC_SCALE_KOUT], sv = sc[SC_SCALE_VOUT];
  for (int i = blockIdx.x * 256 + threadIdx.x; i < 2 * n1; i += gridDim.x * 256) {
    int isv = i >= n1;
    int j = i - isv * n1;
    int kvh = j / (S_LEN * HD);
    int rem = j - kvh * S_LEN * HD;
    int s = rem / HD, d = rem - s * HD;
    float x = (isv ? VB : KB)[(size_t)s * (NKV * HD) + kvh * HD + d];
    float ss = isv ? sv : sk;
    dout[(size_t)S_LEN * HID + i] = clampq(rintf(x / ss)) * ss;
  }
}

// build updated quantized caches: old tail double-quantized, fresh entries single-quantized
__global__ __launch_bounds__(256) void k_build_cache(const float* __restrict__ ck, const float* __restrict__ cv,
                                                     const float* __restrict__ KB, const float* __restrict__ VB,
                                                     float* __restrict__ KC, float* __restrict__ VC,
                                                     const float* __restrict__ sc) {
  const int n1 = NKV * CL * HD;
  float sck = sc[SC_SCALE_CK], scv = sc[SC_SCALE_CV];
  float skn = sc[SC_SCALE_KNEW], svn = sc[SC_SCALE_VNEW];
  for (int i = blockIdx.x * 256 + threadIdx.x; i < 2 * n1; i += gridDim.x * 256) {
    int isv = i >= n1;
    int j = i - isv * n1;
    int kvh = j / (CL * HD);
    int rem = j - kvh * CL * HD;
    int t = rem / HD, d = rem - t * HD;
    float s1 = isv ? scv : sck, s2 = isv ? svn : skn;
    float outv;
    if (t < TAILN) {
      float x = (isv ? cv : ck)[(size_t)kvh * CL * HD + (size_t)(t + S_LEN) * HD + d];
      float v1 = clampq(rintf(x / s1)) * s1;
      outv = clampq(rintf(v1 / s2)) * s2;
    } else {
      float x = (isv ? VB : KB)[(size_t)(t - TAILN) * (NKV * HD) + kvh * HD + d];
      outv = clampq(rintf(x / s2)) * s2;
    }
    (isv ? VC : KC)[j] = outv;
  }
}

// pass 1: per (head, 64 q-rows, half of keys) -> partial (m,l)
__global__ __launch_bounds__(256) void k_attn1(const float* __restrict__ QQ, const float* __restrict__ KC,
                                               const float* __restrict__ mask, float* __restrict__ PM,
                                               float* __restrict__ PL) {
  int bid = blockIdx.x;
  int tc = bid & 1, rt = (bid >> 1) & 7, h = bid >> 4, kv = h >> 2;
  int r0 = rt * 64;
  const float* Kb = KC + (size_t)kv * CL * HD;
  __shared__ float Qs[64][HD + 1];
  __shared__ float KT[HD][68];
  __shared__ float red[64][16];
  __shared__ float Mrow[64], Lrow[64], NewM[64];
  int tid = threadIdx.x;
  for (int i = tid; i < 64 * (HD / 4); i += 256) {
    int r = i >> 5, c = (i & 31) << 2;
    float4 v = *(const float4*)&QQ[(size_t)(r0 + r) * HID + h * HD + c];
    Qs[r][c] = v.x; Qs[r][c + 1] = v.y; Qs[r][c + 2] = v.z; Qs[r][c + 3] = v.w;
  }
  if (tid < 64) { Mrow[tid] = -INFINITY; Lrow[tid] = 0.f; }
  int ty = tid >> 4, tx = tid & 15;
  int tstart = tc * (CL / 2), tend = tstart + (CL / 2);
  for (int t0 = tstart; t0 < tend; t0 += 64) {
    __syncthreads();
    for (int i = tid; i < 64 * (HD / 4); i += 256) {
      int t = i >> 5, c = (i & 31) << 2;
      float4 v = *(const float4*)&Kb[(size_t)(t0 + t) * HD + c];
      KT[c][t] = v.x; KT[c + 1][t] = v.y; KT[c + 2][t] = v.z; KT[c + 3][t] = v.w;
    }
    __syncthreads();
    float acc[4][4] = {};
    for (int kk = 0; kk < HD; ++kk) {
      float qa[4];
      #pragma unroll
      for (int i = 0; i < 4; i++) qa[i] = Qs[ty * 4 + i][kk];
      float4 kb = *(const float4*)&KT[kk][tx * 4];
      #pragma unroll
      for (int i = 0; i < 4; i++) {
        acc[i][0] = fmaf(qa[i], kb.x, acc[i][0]);
        acc[i][1] = fmaf(qa[i], kb.y, acc[i][1]);
        acc[i][2] = fmaf(qa[i], kb.z, acc[i][2]);
        acc[i][3] = fmaf(qa[i], kb.w, acc[i][3]);
      }
    }
    float scv[4][4];
    #pragma unroll
    for (int i = 0; i < 4; i++) {
      const float* mrow = &mask[(size_t)(r0 + ty * 4 + i) * CL + t0 + tx * 4];
      float best = -INFINITY;
      #pragma unroll
      for (int j = 0; j < 4; j++) {
        float v = acc[i][j] * INV_SQRT_HD + mrow[j];
        scv[i][j] = v;
        best = fmaxf(best, v);
      }
      red[ty * 4 + i][tx] = best;
    }
    __syncthreads();
    if (tid < 64) {
      float nm = Mrow[tid];
      #pragma unroll
      for (int x = 0; x < 16; x++) nm = fmaxf(nm, red[tid][x]);
      NewM[tid] = nm;
    }
    __syncthreads();
    #pragma unroll
    for (int i = 0; i < 4; i++) {
      float nm = NewM[ty * 4 + i];
      float ps = 0.f;
      #pragma unroll
      for (int j = 0; j < 4; j++) ps += expf(scv[i][j] - nm);
      red[ty * 4 + i][tx] = ps;
    }
    __syncthreads();
    if (tid < 64) {
      float ssum = 0.f;
      #pragma unroll
      for (int x = 0; x < 16; x++) ssum += red[tid][x];
      Lrow[tid] = Lrow[tid] * expf(Mrow[tid] - NewM[tid]) + ssum;
      Mrow[tid] = NewM[tid];
    }
  }
  __syncthreads();
  if (tid < 64) {
    PM[((size_t)tc * NH + h) * S_LEN + r0 + tid] = Mrow[tid];
    PL[((size_t)tc * NH + h) * S_LEN + r0 + tid] = Lrow[tid];
  }
}

__global__ __launch_bounds__(256) void k_merge(const float* __restrict__ PM, const float* __restrict__ PL,
                                               float* __restrict__ MLm, float* __restrict__ MLl, float* sc) {
  int idx = blockIdx.x * 256 + threadIdx.x;   // NH*S_LEN = 8192 exactly
  float m0 = PM[idx], m1 = PM[NH * S_LEN + idx];
  float l0 = PL[idx], l1 = PL[NH * S_LEN + idx];
  float m = fmaxf(m0, m1);
  float l = l0 * expf(m0 - m) + l1 * expf(m1 - m);
  MLm[idx] = m; MLl[idx] = l;
  float lm = blockMin256(l);
  if (threadIdx.x == 0) atomicMinPosF(&sc[SC_MIN_L], lm);
}

// pass 2: recompute scores (identical fmaf chain), quantize p, accumulate p_int * v_q
__global__ __launch_bounds__(256) void k_attn2(const float* __restrict__ QQ, const float* __restrict__ KC,
                                               const float* __restrict__ VC, const float* __restrict__ mask,
                                               const float* __restrict__ MLm, const float* __restrict__ MLl,
                                               float* __restrict__ AO, float* __restrict__ sc) {
  int bid = blockIdx.x;
  int rt = bid & 15, h = bid >> 4, kv = h >> 2;
  int r0 = rt * 32;
  const float* Kb = KC + (size_t)kv * CL * HD;
  const float* Vb = VC + (size_t)kv * CL * HD;
  __shared__ float Qs[32][HD + 1];
  __shared__ float KV[HD][132];
  __shared__ float Ps[32][HD];
  int tid = threadIdx.x;
  for (int i = tid; i < 32 * (HD / 4); i += 256) {
    int r = i >> 5, c = (i & 31) << 2;
    float4 v = *(const float4*)&QQ[(size_t)(r0 + r) * HID + h * HD + c];
    Qs[r][c] = v.x; Qs[r][c + 1] = v.y; Qs[r][c + 2] = v.z; Qs[r][c + 3] = v.w;
  }
  int ry = tid >> 5, cx = tid & 31;
  float mreg[4], lreg[4];
  #pragma unroll
  for (int i = 0; i < 4; i++) {
    mreg[i] = MLm[h * S_LEN + r0 + ry * 4 + i];
    lreg[i] = MLl[h * S_LEN + r0 + ry * 4 + i];
  }
  float sp = sc[SC_SCALE_P];
  float acc[4][4] = {};
  for (int t0 = 0; t0 < CL; t0 += 128) {
    __syncthreads();
    for (int i = tid; i < 128 * (HD / 4); i += 256) {   // K transposed: KV[d][t]
      int t = i >> 5, c = (i & 31) << 2;
      float4 v = *(const float4*)&Kb[(size_t)(t0 + t) * HD + c];
      KV[c][t] = v.x; KV[c + 1][t] = v.y; KV[c + 2][t] = v.z; KV[c + 3][t] = v.w;
    }
    __syncthreads();
    float a2[4][4] = {};
    for (int kk = 0; kk < HD; ++kk) {
      float qa[4];
      #pragma unroll
      for (int i = 0; i < 4; i++) qa[i] = Qs[ry * 4 + i][kk];
      float4 kb = *(const float4*)&KV[kk][cx * 4];
      #pragma unroll
      for (int i = 0; i < 4; i++) {
        a2[i][0] = fmaf(qa[i], kb.x, a2[i][0]);
        a2[i][1] = fmaf(qa[i], kb.y, a2[i][1]);
        a2[i][2] = fmaf(qa[i], kb.z, a2[i][2]);
        a2[i][3] = fmaf(qa[i], kb.w, a2[i][3]);
      }
    }
    #pragma unroll
    for (int i = 0; i < 4; i++) {
      const float* mrow = &mask[(size_t)(r0 + ry * 4 + i) * CL + t0 + cx * 4];
      #pragma unroll
      for (int j = 0; j < 4; j++) {
        float s_ = a2[i][j] * INV_SQRT_HD + mrow[j];
        float p = expf(s_ - mreg[i]) / lreg[i];
        float q = fminf(rintf(p / sp), 127.f);
        Ps[ry * 4 + i][cx * 4 + j] = q;
      }
    }
    __syncthreads();
    for (int i = tid; i < 128 * (HD / 4); i += 256) {   // V row-major: KV[t][d]
      int t = i >> 5, c = (i & 31) << 2;
      float4 v = *(const float4*)&Vb[(size_t)(t0 + t) * HD + c];
      KV[t][c] = v.x; KV[t][c + 1] = v.y; KV[t][c + 2] = v.z; KV[t][c + 3] = v.w;
    }
    __syncthreads();
    for (int t = 0; t < 128; ++t) {
      float pv[4];
      #pragma unroll
      for (int i = 0; i < 4; i++) pv[i] = Ps[ry * 4 + i][t];
      float4 vv = *(const float4*)&KV[t][cx * 4];
      #pragma unroll
      for (int i = 0; i < 4; i++) {
        acc[i][0] = fmaf(pv[i], vv.x, acc[i][0]);
        acc[i][1] = fmaf(pv[i], vv.y, acc[i][1]);
        acc[i][2] = fmaf(pv[i], vv.z, acc[i][2]);
        acc[i][3] = fmaf(pv[i], vv.w, acc[i][3]);
      }
    }
  }
  float am = 0.f;
  #pragma unroll
  for (int i = 0; i < 4; i++)
    #pragma unroll
    for (int j = 0; j < 4; j++) {
      float val = acc[i][j] * sp;
      AO[(size_t)(r0 + ry * 4 + i) * HID + h * HD + cx * 4 + j] = val;
      am = fmaxf(am, fabsf(val));
    }
  am = blockMax256(am);
  if (tid == 0) atomicMaxPosF(&sc[SC_AMAX_AO], am);
}

extern "C" void kernel_launch(void* const* d_in, const int* in_sizes, int n_in,
                              void* d_out, int out_size, void* d_ws, size_t ws_size,
                              hipStream_t stream) {
  const float* hidden = (const float*)d_in[0];
  const float* cosb   = (const float*)d_in[1];
  const float* sinb   = (const float*)d_in[2];
  const float* cachek = (const float*)d_in[3];
  const float* cachev = (const float*)d_in[4];
  const float* mask   = (const float*)d_in[5];
  const float* Wq     = (const float*)d_in[6];
  const float* bq     = (const float*)d_in[7];
  const float* Wk     = (const float*)d_in[8];
  const float* bk     = (const float*)d_in[9];
  const float* Wv     = (const float*)d_in[10];
  const float* bv     = (const float*)d_in[11];
  const float* Wo     = (const float*)d_in[12];
  float* out = (float*)d_out;
  float* ws = (float*)d_ws;

  size_t off = 0;
  float* SC  = ws + off; off += 64;
  float* XQ  = ws + off; off += (size_t)S_LEN * HID;
  float* WQQ = ws + off; off += (size_t)HID * HID;
  float* WKQ = ws + off; off += (size_t)NKV * HD * HID;
  float* WVQ = ws + off; off += (size_t)NKV * HD * HID;
  float* WOQ = ws + off; off += (size_t)HID * HID;
  float* QB  = ws + off; off += (size_t)S_LEN * NH * HD;
  float* KB  = ws + off; off += (size_t)S_LEN * NKV * HD;
  float* VB  = ws + off; off += (size_t)S_LEN * NKV * HD;
  float* KC  = ws + off; off += (size_t)NKV * CL * HD;
  float* VC  = ws + off; off += (size_t)NKV * CL * HD;
  float* MLm = ws + off; off += (size_t)NH * S_LEN;
  float* MLl = ws + off; off += (size_t)NH * S_LEN;
  float* PM  = ws + off; off += (size_t)2 * NH * S_LEN;
  float* PL  = ws + off; off += (size_t)2 * NH * S_LEN;
  float* AO  = ws + off; off += (size_t)S_LEN * HID;

  k_init<<<1, 64, 0, stream>>>(SC);
  k_absmax4<<<1024, 256, 0, stream>>>(hidden, S_LEN * HID / 4, &SC[SC_AMAX_X]);
  k_absmax_cache<<<2048, 256, 0, stream>>>(cachek, &SC[SC_AMAX_CK], &SC[SC_AMAX_CK_TAIL]);
  k_absmax_cache<<<2048, 256, 0, stream>>>(cachev, &SC[SC_AMAX_CV], &SC[SC_AMAX_CV_TAIL]);
  k_quant_w<<<HID, 256, 0, stream>>>(Wq, WQQ, HID);
  k_quant_w<<<NKV * HD, 256, 0, stream>>>(Wk, WKQ, HID);
  k_quant_w<<<NKV * HD, 256, 0, stream>>>(Wv, WVQ, HID);
  k_quant_w<<<HID, 256, 0, stream>>>(Wo, WOQ, HID);
  k_combine1<<<1, 1, 0, stream>>>(SC);
  k_quant_buf<<<1024, 256, 0, stream>>>(hidden, XQ, S_LEN * HID / 4, SC, SC_SCALE_X);
  {
    dim3 gq(HID / 64, S_LEN / 64);
    k_gemm<<<gq, 256, 0, stream>>>(XQ, WQQ, bq, QB, S_LEN, HID, HID);
    dim3 gk(NKV * HD / 64, S_LEN / 64);
    k_gemm<<<gk, 256, 0, stream>>>(XQ, WKQ, bk, KB, S_LEN, NKV * HD, HID);
    k_gemm<<<gk, 256, 0, stream>>>(XQ, WVQ, bv, VB, S_LEN, NKV * HD, HID);
  }
  k_rope<<<2048, 256, 0, stream>>>(QB, cosb, sinb, NH, &SC[SC_AMAX_Q]);
  k_rope<<<512, 256, 0, stream>>>(KB, cosb, sinb, NKV, &SC[SC_AMAX_K]);
  k_absmax4<<<256, 256, 0, stream>>>(VB, NKV * S_LEN * HD / 4, &SC[SC_AMAX_V]);
  k_combine2<<<1, 1, 0, stream>>>(SC);
  k_kvout<<<2048, 256, 0, stream>>>(KB, VB, out, SC);
  k_build_cache<<<2048, 256, 0, stream>>>(cachek, cachev, KB, VB, KC, VC, SC);
  k_quant_buf<<<1024, 256, 0, stream>>>(QB, QB, S_LEN * HID / 4, SC, SC_SCALE_Q);
  k_attn1<<<256, 256, 0, stream>>>(QB, KC, mask, PM, PL);
  k_merge<<<NH * S_LEN / 256, 256, 0, stream>>>(PM, PL, MLm, MLl, SC);
  k_combine3<<<1, 1, 0, stream>>>(SC);
  k_attn2<<<256, 256, 0, stream>>>(QB, KC, VC, mask, MLm, MLl, AO, SC);
  k_combine4<<<1, 1, 0, stream>>>(SC);
  k_quant_buf<<<1024, 256, 0, stream>>>(AO, AO, S_LEN * HID / 4, SC, SC_SCALE_O);
  {
    dim3 gq(HID / 64, S_LEN / 64);
    k_gemm<<<gq, 256, 0, stream>>>(AO, WOQ, nullptr, out, S_LEN, HID, HID);
  }
  (void)in_sizes; (void)n_in; (void)out_size; (void)ws_size;
}

// Round 2
// 518.561 us; speedup vs baseline: 4.2454x; 4.2454x over previous
//
#include <hip/hip_runtime.h>
#include <math.h>

#define S_LEN 512
#define HID 2048
#define NH 16
#define NKV 4
#define HD 128
#define CL 8192
#define TAILN (CL - S_LEN)
#define KS 4                  // key partitions for attention passes
#define KCHUNK (CL / KS)      // 2048 keys per partition
#define INV_SQRT_HD 0.08838834764831845f

typedef unsigned short u16;
typedef __attribute__((ext_vector_type(8))) unsigned short u16x8;
typedef __attribute__((ext_vector_type(4))) unsigned short u16x4;
typedef __attribute__((ext_vector_type(8))) short bf16x8;
typedef __attribute__((ext_vector_type(4))) float f32x4;

enum {
  SC_AMAX_X = 0, SC_AMAX_CK, SC_AMAX_CK_TAIL, SC_AMAX_CV, SC_AMAX_CV_TAIL,
  SC_AMAX_Q, SC_AMAX_K, SC_AMAX_V, SC_AMAX_AO, SC_MIN_L,
  SC_SCALE_X, SC_SCALE_CK, SC_SCALE_CV, SC_SCALE_Q, SC_SCALE_KNEW,
  SC_SCALE_VNEW, SC_SCALE_KOUT, SC_SCALE_VOUT, SC_SCALE_P, SC_SCALE_O,
  SC_RSP, SC_PSV,
  SC_NUM
};

__device__ __forceinline__ float warpMax64(float v) {
  #pragma unroll
  for (int o = 32; o; o >>= 1) v = fmaxf(v, __shfl_down(v, o, 64));
  return v;
}
__device__ __forceinline__ float warpMin64(float v) {
  #pragma unroll
  for (int o = 32; o; o >>= 1) v = fminf(v, __shfl_down(v, o, 64));
  return v;
}
// requires blockDim.x == 256
__device__ __forceinline__ float blockMax256(float v) {
  __shared__ float sm_[4];
  __syncthreads();
  v = warpMax64(v);
  if ((threadIdx.x & 63) == 0) sm_[threadIdx.x >> 6] = v;
  __syncthreads();
  return fmaxf(fmaxf(sm_[0], sm_[1]), fmaxf(sm_[2], sm_[3]));
}
__device__ __forceinline__ float blockMin256(float v) {
  __shared__ float sn_[4];
  __syncthreads();
  v = warpMin64(v);
  if ((threadIdx.x & 63) == 0) sn_[threadIdx.x >> 6] = v;
  __syncthreads();
  return fminf(fminf(sn_[0], sn_[1]), fminf(sn_[2], sn_[3]));
}
__device__ __forceinline__ void atomicMaxPosF(float* a, float v) {
  atomicMax((unsigned int*)a, __float_as_uint(v));
}
__device__ __forceinline__ void atomicMinPosF(float* a, float v) {
  atomicMin((unsigned int*)a, __float_as_uint(v));
}
__device__ __forceinline__ float clampq(float q) {
  return fminf(fmaxf(q, -128.f), 127.f);
}
__device__ __forceinline__ u16 bf16bits(float f) {
  // exact for small integers (<= 8 significant bits)
  return (u16)(__float_as_uint(f) >> 16);
}

__global__ void k_init(float* sc) {
  int i = threadIdx.x;
  if (i < SC_NUM) sc[i] = (i == SC_MIN_L) ? INFINITY : 0.f;
}

__global__ __launch_bounds__(256) void k_absmax4(const float* __restrict__ x, int n4, float* slot) {
  float m = 0.f;
  const float4* x4 = (const float4*)x;
  for (int i = blockIdx.x * 256 + threadIdx.x; i < n4; i += gridDim.x * 256) {
    float4 v = x4[i];
    m = fmaxf(m, fmaxf(fmaxf(fabsf(v.x), fabsf(v.y)), fmaxf(fabsf(v.z), fabsf(v.w))));
  }
  m = blockMax256(m);
  if (threadIdx.x == 0) atomicMaxPosF(slot, m);
}

__global__ __launch_bounds__(256) void k_absmax_cache(const float* __restrict__ x, float* sfull, float* stail) {
  float mf = 0.f, mt = 0.f;
  const float4* x4 = (const float4*)x;
  const int n4 = NKV * CL * HD / 4;
  for (int i = blockIdx.x * 256 + threadIdx.x; i < n4; i += gridDim.x * 256) {
    float4 v = x4[i];
    float a = fmaxf(fmaxf(fabsf(v.x), fabsf(v.y)), fmaxf(fabsf(v.z), fabsf(v.w)));
    mf = fmaxf(mf, a);
    int t = (i >> 5) & (CL - 1);   // HD/4 = 32 float4 per row
    if (t >= S_LEN) mt = fmaxf(mt, a);
  }
  mf = blockMax256(mf);
  mt = blockMax256(mt);
  if (threadIdx.x == 0) { atomicMaxPosF(sfull, mf); atomicMaxPosF(stail, mt); }
}

// per-out-channel weight fake-quant -> bf16 integer codes + per-row scale. K == HID.
__global__ __launch_bounds__(256) void k_quant_w_b(const float* __restrict__ W, u16* __restrict__ Wb,
                                                   float* __restrict__ SW) {
  size_t base = (size_t)blockIdx.x * HID;
  const float4* w4 = (const float4*)(W + base);
  const int n4 = HID / 4;
  float am = 0.f;
  for (int i = threadIdx.x; i < n4; i += 256) {
    float4 v = w4[i];
    am = fmaxf(am, fmaxf(fmaxf(fabsf(v.x), fabsf(v.y)), fmaxf(fabsf(v.z), fabsf(v.w))));
  }
  am = blockMax256(am);
  float s = fmaxf(am, 1e-8f) / 127.f;
  if (threadIdx.x == 0) SW[blockIdx.x] = s;
  for (int i = threadIdx.x; i < n4; i += 256) {
    float4 v = w4[i];
    u16x4 o;
    o[0] = bf16bits(clampq(rintf(v.x / s)));
    o[1] = bf16bits(clampq(rintf(v.y / s)));
    o[2] = bf16bits(clampq(rintf(v.z / s)));
    o[3] = bf16bits(clampq(rintf(v.w / s)));
    *(u16x4*)(Wb + base + (size_t)i * 4) = o;
  }
}

// activation fake-quant -> bf16 integer codes, layout preserved
__global__ __launch_bounds__(256) void k_quant_act_b(const float* __restrict__ in, u16* __restrict__ outp,
                                                     int n4, const float* __restrict__ sc, int slot) {
  float s = sc[slot];
  const float4* i4 = (const float4*)in;
  for (int i = blockIdx.x * 256 + threadIdx.x; i < n4; i += gridDim.x * 256) {
    float4 v = i4[i];
    u16x4 o;
    o[0] = bf16bits(clampq(rintf(v.x / s)));
    o[1] = bf16bits(clampq(rintf(v.y / s)));
    o[2] = bf16bits(clampq(rintf(v.z / s)));
    o[3] = bf16bits(clampq(rintf(v.w / s)));
    *(u16x4*)(outp + (size_t)i * 4) = o;
  }
}

// QB f32 [S][NH*HD] -> QI bf16-int [NH][S][HD]
__global__ __launch_bounds__(256) void k_quant_q(const float* __restrict__ QB, u16* __restrict__ QI,
                                                 const float* __restrict__ sc) {
  int idx = blockIdx.x * 256 + threadIdx.x;   // S*NH*HD/4 = 262144
  float s = sc[SC_SCALE_Q];
  int e = idx * 4;
  int srow = e >> 11, rem = e & 2047;
  int h = rem >> 7, d = rem & 127;
  float4 v = *(const float4*)&QB[e];
  u16x4 o;
  o[0] = bf16bits(clampq(rintf(v.x / s)));
  o[1] = bf16bits(clampq(rintf(v.y / s)));
  o[2] = bf16bits(clampq(rintf(v.z / s)));
  o[3] = bf16bits(clampq(rintf(v.w / s)));
  *(u16x4*)(QI + ((size_t)h * S_LEN + srow) * HD + d) = o;
}

__global__ void k_combine1(float* sc) {
  sc[SC_SCALE_X]  = fmaxf(sc[SC_AMAX_X],  1e-8f) / 127.f;
  sc[SC_SCALE_CK] = fmaxf(sc[SC_AMAX_CK], 1e-8f) / 127.f;
  sc[SC_SCALE_CV] = fmaxf(sc[SC_AMAX_CV], 1e-8f) / 127.f;
}
__global__ void k_combine2(float* sc) {
  float sck = sc[SC_SCALE_CK], scv = sc[SC_SCALE_CV];
  float tqk = fminf(rintf(sc[SC_AMAX_CK_TAIL] / sck), 127.f) * sck;
  float tqv = fminf(rintf(sc[SC_AMAX_CV_TAIL] / scv), 127.f) * scv;
  sc[SC_SCALE_Q]    = fmaxf(sc[SC_AMAX_Q], 1e-8f) / 127.f;
  sc[SC_SCALE_KOUT] = fmaxf(sc[SC_AMAX_K], 1e-8f) / 127.f;
  sc[SC_SCALE_VOUT] = fmaxf(sc[SC_AMAX_V], 1e-8f) / 127.f;
  sc[SC_SCALE_KNEW] = fmaxf(fmaxf(tqk, sc[SC_AMAX_K]), 1e-8f) / 127.f;
  sc[SC_SCALE_VNEW] = fmaxf(fmaxf(tqv, sc[SC_AMAX_V]), 1e-8f) / 127.f;
}
__global__ void k_combine3(float* sc) {
  float sp = fmaxf(1.0f / sc[SC_MIN_L], 1e-8f) / 127.f;
  sc[SC_SCALE_P] = sp;
  sc[SC_RSP] = 1.0f / sp;
  sc[SC_PSV] = sp * sc[SC_SCALE_VNEW];
}
__global__ void k_combine4(float* sc) {
  sc[SC_SCALE_O] = fmaxf(sc[SC_AMAX_AO], 1e-8f) / 127.f;
}

// integer-domain MFMA GEMM: C[M,N] = (Aint[M,K] x Bint[N,K]^T) * (sx*SW[col]) + bias
// 64x64 tile, BK=64, 4 waves (2x2 of 32x32)
__global__ __launch_bounds__(256) void k_gemm_q(const u16* __restrict__ A, const u16* __restrict__ B,
                                                const float* __restrict__ SW, const float* __restrict__ bias,
                                                const float* __restrict__ sc, int sxslot,
                                                float* __restrict__ C, int M, int N, int K) {
  __shared__ u16 Al[64 * 64];
  __shared__ u16 Bl[64 * 64];
  int tid = threadIdx.x, lane = tid & 63, w = tid >> 6;
  int g = lane >> 4, c = lane & 15;
  int wy = w >> 1, wx = w & 1;
  int r0 = blockIdx.y * 64, c0 = blockIdx.x * 64;
  float sx = sc[sxslot];
  f32x4 acc[2][2] = {};
  for (int k0 = 0; k0 < K; k0 += 64) {
    __syncthreads();
    #pragma unroll
    for (int i = 0; i < 2; i++) {
      int b = tid + i * 256;
      int row = b >> 3, c8d = b & 7, c8s = c8d ^ (row & 7);
      *(u16x8*)(Al + row * 64 + c8d * 8) = *(const u16x8*)(A + (size_t)(r0 + row) * K + k0 + c8s * 8);
    }
    #pragma unroll
    for (int i = 0; i < 2; i++) {
      int b = tid + i * 256;
      int row = b >> 3, c8d = b & 7, c8s = c8d ^ (row & 7);
      *(u16x8*)(Bl + row * 64 + c8d * 8) = *(const u16x8*)(B + (size_t)(c0 + row) * K + k0 + c8s * 8);
    }
    __syncthreads();
    #pragma unroll
    for (int ks = 0; ks < 2; ks++) {
      bf16x8 af[2], bf[2];
      #pragma unroll
      for (int a = 0; a < 2; a++) {
        int row = wy * 32 + a * 16 + c;
        af[a] = *(const bf16x8*)(Al + row * 64 + (((4 * ks + g) ^ (row & 7)) * 8));
      }
      #pragma unroll
      for (int b = 0; b < 2; b++) {
        int row = wx * 32 + b * 16 + c;
        bf[b] = *(const bf16x8*)(Bl + row * 64 + (((4 * ks + g) ^ (row & 7)) * 8));
      }
      #pragma unroll
      for (int a = 0; a < 2; a++)
        #pragma unroll
        for (int b = 0; b < 2; b++)
          acc[a][b] = __builtin_amdgcn_mfma_f32_16x16x32_bf16(af[a], bf[b], acc[a][b], 0, 0, 0);
    }
  }
  #pragma unroll
  for (int a = 0; a < 2; a++)
    #pragma unroll
    for (int b = 0; b < 2; b++) {
      int col = c0 + wx * 32 + b * 16 + c;
      float sca = sx * SW[col];
      float bs = bias ? bias[col] : 0.f;
      #pragma unroll
      for (int r = 0; r < 4; r++) {
        int row = r0 + wy * 32 + a * 16 + 4 * g + r;
        C[(size_t)row * N + col] = acc[a][b][r] * sca + bs;
      }
    }
}

// in-place RoPE on [S, nheads*HD] + amax reduction
__global__ __launch_bounds__(256) void k_rope(float* __restrict__ B, const float* __restrict__ cosb,
                                              const float* __restrict__ sinb, int nheads,
                                              float* __restrict__ amax_slot) {
  int n = S_LEN * nheads * 64;
  int stride = nheads * HD;
  float am = 0.f;
  for (int idx = blockIdx.x * 256 + threadIdx.x; idx < n; idx += gridDim.x * 256) {
    int s = idx / (nheads * 64);
    int rem = idx - s * nheads * 64;
    int h = rem >> 6, d = rem & 63;
    float c1 = cosb[s * HD + d], s1 = sinb[s * HD + d];
    float c2 = cosb[s * HD + d + 64], s2 = sinb[s * HD + d + 64];
    float* p = &B[(size_t)s * stride + h * HD + d];
    float x1 = p[0], x2 = p[64];
    float y1 = x1 * c1 - x2 * s1;
    float y2 = x2 * c2 + x1 * s2;
    p[0] = y1; p[64] = y2;
    am = fmaxf(am, fmaxf(fabsf(y1), fabsf(y2)));
  }
  am = blockMax256(am);
  if (threadIdx.x == 0) atomicMaxPosF(amax_slot, am);
}

// k_out / v_out (fq of fresh k,v) into d_out after the main output
__global__ __launch_bounds__(256) void k_kvout(const float* __restrict__ KB, const float* __restrict__ VB,
                                               float* __restrict__ dout, const float* __restrict__ sc) {
  const int n1 = NKV * S_LEN * HD;
  float sk = sc[SC_SCALE_KOUT], sv = sc[SC_SCALE_VOUT];
  for (int i = blockIdx.x * 256 + threadIdx.x; i < 2 * n1; i += gridDim.x * 256) {
    int isv = i >= n1;
    int j = i - isv * n1;
    int kvh = j / (S_LEN * HD);
    int rem = j - kvh * S_LEN * HD;
    int s = rem / HD, d = rem - s * HD;
    float x = (isv ? VB : KB)[(size_t)s * (NKV * HD) + kvh * HD + d];
    float ss = isv ? sv : sk;
    dout[(size_t)S_LEN * HID + i] = clampq(rintf(x / ss)) * ss;
  }
}

// build updated caches as bf16 INTEGER codes (value = int * SCALE_{K,V}NEW)
__global__ __launch_bounds__(256) void k_build_cache_b(const float* __restrict__ ck, const float* __restrict__ cv,
                                                       const float* __restrict__ KB, const float* __restrict__ VB,
                                                       u16* __restrict__ KCb, u16* __restrict__ VCb,
                                                       const float* __restrict__ sc) {
  const int n1 = NKV * CL * HD;
  float sck = sc[SC_SCALE_CK], scv = sc[SC_SCALE_CV];
  float skn = sc[SC_SCALE_KNEW], svn = sc[SC_SCALE_VNEW];
  for (int i = blockIdx.x * 256 + threadIdx.x; i < 2 * n1; i += gridDim.x * 256) {
    int isv = i >= n1;
    int j = i - isv * n1;
    int kvh = j / (CL * HD);
    int rem = j - kvh * CL * HD;
    int t = rem / HD, d = rem - t * HD;
    float s1 = isv ? scv : sck, s2 = isv ? svn : skn;
    float outi;
    if (t < TAILN) {
      float x = (isv ? cv : ck)[(size_t)kvh * CL * HD + (size_t)(t + S_LEN) * HD + d];
      float v1 = clampq(rintf(x / s1)) * s1;
      outi = clampq(rintf(v1 / s2));
    } else {
      float x = (isv ? VB : KB)[(size_t)(t - TAILN) * (NKV * HD) + kvh * HD + d];
      outi = clampq(rintf(x / s2));
    }
    (isv ? VCb : KCb)[j] = bf16bits(outi);
  }
}

// VCb [NKV][CL][HD] -> VT [NKV][HD][CL]
__global__ __launch_bounds__(256) void k_transpose_v(const u16* __restrict__ VCb, u16* __restrict__ VT) {
  __shared__ u16 T[64][72];
  int bid = blockIdx.x;
  int kv = bid >> 8, rem = bid & 255, tb = rem >> 1, db = rem & 1;
  int tid = threadIdx.x;
  int r = tid >> 3, cb = tid & 7;
  #pragma unroll
  for (int i = 0; i < 2; i++) {
    int row = r + i * 32;
    u16x8 v = *(const u16x8*)(VCb + ((size_t)kv * CL + tb * 64 + row) * HD + db * 64 + cb * 8);
    *(u16x8*)&T[row][cb * 8] = v;
  }
  __syncthreads();
  #pragma unroll
  for (int i = 0; i < 2; i++) {
    int drow = r + i * 32;
    u16x8 v;
    #pragma unroll
    for (int j = 0; j < 8; j++) v[j] = T[cb * 8 + j][drow];
    *(u16x8*)(VT + ((size_t)kv * HD + db * 64 + drow) * CL + tb * 64 + cb * 8) = v;
  }
}

// pass 1: MFMA QK^T, per-lane online (m,l), shfl merge. grid = NH*8*KS
__global__ __launch_bounds__(256) void k_mattn1(const u16* __restrict__ QI, const u16* __restrict__ KCb,
                                                const float* __restrict__ mask, const float* __restrict__ sc,
                                                float* __restrict__ PM, float* __restrict__ PL) {
  __shared__ u16 Kl[64 * HD];
  int bid = blockIdx.x;
  int kc = bid & 3, qb = (bid >> 2) & 7, h = bid >> 5, kv = h >> 2;
  int tid = threadIdx.x, lane = tid & 63, w = tid >> 6, g = lane >> 4, c = lane & 15;
  float sscale = sc[SC_SCALE_Q] * sc[SC_SCALE_KNEW] * INV_SQRT_HD;
  int q0 = qb * 64 + w * 16;
  bf16x8 qf[4];
  {
    const u16* qrow = QI + ((size_t)h * S_LEN + q0 + c) * HD + g * 8;
    #pragma unroll
    for (int ds = 0; ds < 4; ds++) qf[ds] = *(const bf16x8*)(qrow + 32 * ds);
  }
  float m[4], l[4];
  #pragma unroll
  for (int r = 0; r < 4; r++) { m[r] = -INFINITY; l[r] = 0.f; }
  int qlane = q0 + 4 * g;
  int kbase0 = kc * KCHUNK;
  const u16* Kg = KCb + (size_t)kv * CL * HD;
  for (int kb = 0; kb < KCHUNK; kb += 64) {
    int kbase = kbase0 + kb;
    __syncthreads();
    #pragma unroll
    for (int i = 0; i < 4; i++) {
      int b = tid + i * 256;
      int row = b >> 4, c8d = b & 15, c8s = c8d ^ (row & 7);
      *(u16x8*)(Kl + row * HD + c8d * 8) = *(const u16x8*)(Kg + (size_t)(kbase + row) * HD + c8s * 8);
    }
    __syncthreads();
    #pragma unroll
    for (int kf = 0; kf < 4; kf++) {
      f32x4 s4 = {0.f, 0.f, 0.f, 0.f};
      int krow = kf * 16 + c;
      #pragma unroll
      for (int ds = 0; ds < 4; ds++) {
        bf16x8 kf8 = *(const bf16x8*)(Kl + krow * HD + (((4 * ds + g) ^ (krow & 7)) * 8));
        s4 = __builtin_amdgcn_mfma_f32_16x16x32_bf16(qf[ds], kf8, s4, 0, 0, 0);
      }
      int key = kbase + kf * 16 + c;
      #pragma unroll
      for (int r = 0; r < 4; r++) {
        float v = fmaf(s4[r], sscale, mask[(size_t)(qlane + r) * CL + key]);
        float nm = fmaxf(m[r], v);
        l[r] = l[r] * __expf(m[r] - nm) + __expf(v - nm);
        m[r] = nm;
      }
    }
  }
  #pragma unroll
  for (int r = 0; r < 4; r++) {
    #pragma unroll
    for (int off = 1; off < 16; off <<= 1) {
      float om = __shfl_xor(m[r], off, 64);
      float ol = __shfl_xor(l[r], off, 64);
      float nm = fmaxf(m[r], om);
      l[r] = l[r] * __expf(m[r] - nm) + ol * __expf(om - nm);
      m[r] = nm;
    }
  }
  if (c == 0) {
    size_t base = ((size_t)kc * NH + h) * S_LEN + qlane;
    #pragma unroll
    for (int r = 0; r < 4; r++) { PM[base + r] = m[r]; PL[base + r] = l[r]; }
  }
}

__global__ __launch_bounds__(256) void k_merge4(const float* __restrict__ PM, const float* __restrict__ PL,
                                                float* __restrict__ MLm, float* __restrict__ MLl, float* sc) {
  int idx = blockIdx.x * 256 + threadIdx.x;   // NH*S_LEN = 8192
  const int st = NH * S_LEN;
  float m = PM[idx];
  #pragma unroll
  for (int p = 1; p < KS; p++) m = fmaxf(m, PM[p * st + idx]);
  float l = 0.f;
  #pragma unroll
  for (int p = 0; p < KS; p++) l += PL[p * st + idx] * __expf(PM[p * st + idx] - m);
  MLm[idx] = m; MLl[idx] = l;
  float lm = blockMin256(l);
  if (threadIdx.x == 0) atomicMinPosF(&sc[SC_MIN_L], lm);
}

// pass 2: MFMA QK^T (bit-identical), P quant via LDS, MFMA PV. grid = NH*8*KS
__global__ __launch_bounds__(256) void k_mattn2(const u16* __restrict__ QI, const u16* __restrict__ KCb,
                                                const u16* __restrict__ VT, const float* __restrict__ mask,
                                                const float* __restrict__ sc, const float* __restrict__ MLm,
                                                const float* __restrict__ MLl, float* __restrict__ AOp) {
  __shared__ u16 Kl[64 * HD];      // 16KB, swizzled row-major [key][d]
  __shared__ u16 Vl[HD * 64];      // 16KB, swizzled row-major [d][key]
  __shared__ u16 Pl[4 * 16 * 64];  // 8KB, per-wave [q][key], swizzled
  int bid = blockIdx.x;
  int kc = bid & 3, qb = (bid >> 2) & 7, h = bid >> 5, kv = h >> 2;
  int tid = threadIdx.x, lane = tid & 63, w = tid >> 6, g = lane >> 4, c = lane & 15;
  float sscale = sc[SC_SCALE_Q] * sc[SC_SCALE_KNEW] * INV_SQRT_HD;
  float rsp = sc[SC_RSP], psv = sc[SC_PSV];
  int q0 = qb * 64 + w * 16;
  bf16x8 qf[4];
  {
    const u16* qrow = QI + ((size_t)h * S_LEN + q0 + c) * HD + g * 8;
    #pragma unroll
    for (int ds = 0; ds < 4; ds++) qf[ds] = *(const bf16x8*)(qrow + 32 * ds);
  }
  int qlane = q0 + 4 * g;
  float mreg[4], invl[4];
  #pragma unroll
  for (int r = 0; r < 4; r++) {
    mreg[r] = MLm[h * S_LEN + qlane + r];
    invl[r] = 1.0f / MLl[h * S_LEN + qlane + r];
  }
  f32x4 acc[8] = {};
  const u16* Kg = KCb + (size_t)kv * CL * HD;
  const u16* Vg = VT + (size_t)kv * HD * CL;
  int kbase0 = kc * KCHUNK;
  u16* Pw = Pl + w * 1024;
  for (int kb = 0; kb < KCHUNK; kb += 64) {
    int kbase = kbase0 + kb;
    __syncthreads();
    #pragma unroll
    for (int i = 0; i < 4; i++) {    // stage K chunk [64][128]
      int b = tid + i * 256;
      int row = b >> 4, c8d = b & 15, c8s = c8d ^ (row & 7);
      *(u16x8*)(Kl + row * HD + c8d * 8) = *(const u16x8*)(Kg + (size_t)(kbase + row) * HD + c8s * 8);
    }
    #pragma unroll
    for (int i = 0; i < 4; i++) {    // stage V^T chunk [128][64]
      int b = tid + i * 256;
      int row = b >> 3, c8d = b & 7, c8s = c8d ^ (row & 7);
      *(u16x8*)(Vl + row * 64 + c8d * 8) = *(const u16x8*)(Vg + (size_t)row * CL + kbase + c8s * 8);
    }
    __syncthreads();
    // QK^T + softmax + P quant (identical arithmetic to pass 1)
    #pragma unroll
    for (int kf = 0; kf < 4; kf++) {
      f32x4 s4 = {0.f, 0.f, 0.f, 0.f};
      int krow = kf * 16 + c;
      #pragma unroll
      for (int ds = 0; ds < 4; ds++) {
        bf16x8 kf8 = *(const bf16x8*)(Kl + krow * HD + (((4 * ds + g) ^ (krow & 7)) * 8));
        s4 = __builtin_amdgcn_mfma_f32_16x16x32_bf16(qf[ds], kf8, s4, 0, 0, 0);
      }
      int key = kbase + kf * 16 + c;
      #pragma unroll
      for (int r = 0; r < 4; r++) {
        float v = fmaf(s4[r], sscale, mask[(size_t)(qlane + r) * CL + key]);
        float p = __expf(v - mreg[r]) * invl[r];
        float pi = fminf(rintf(p * rsp), 127.f);
        int prow = 4 * g + r, pcol = kf * 16 + c;
        Pw[prow * 64 + (pcol ^ ((prow & 7) << 3))] = bf16bits(pi);
      }
    }
    __syncthreads();
    // PV
    bf16x8 pa[2];
    #pragma unroll
    for (int s = 0; s < 2; s++)
      pa[s] = *(const bf16x8*)(Pw + c * 64 + ((32 * s + 8 * g) ^ ((c & 7) << 3)));
    #pragma unroll
    for (int dt = 0; dt < 8; dt++) {
      #pragma unroll
      for (int s = 0; s < 2; s++) {
        int drow = dt * 16 + c;
        bf16x8 vf = *(const bf16x8*)(Vl + drow * 64 + (((4 * s + g) ^ (drow & 7)) * 8));
        acc[dt] = __builtin_amdgcn_mfma_f32_16x16x32_bf16(pa[s], vf, acc[dt], 0, 0, 0);
      }
    }
  }
  float* outp = AOp + (size_t)kc * S_LEN * HID;
  #pragma unroll
  for (int dt = 0; dt < 8; dt++)
    #pragma unroll
    for (int r = 0; r < 4; r++)
      outp[(size_t)(qlane + r) * HID + h * HD + dt * 16 + c] = acc[dt][r] * psv;
}

__global__ __launch_bounds__(256) void k_combine_ao(const float* __restrict__ AOp, float* __restrict__ AO,
                                                    float* sc) {
  int idx = blockIdx.x * 256 + threadIdx.x;   // S*HID/4 = 262144
  const int st = S_LEN * HID / 4;
  const f32x4* p4 = (const f32x4*)AOp;
  f32x4 a = p4[idx];
  #pragma unroll
  for (int p = 1; p < KS; p++) {
    f32x4 b = p4[p * st + idx];
    a = a + b;
  }
  *((f32x4*)AO + idx) = a;
  float am = fmaxf(fmaxf(fabsf(a[0]), fabsf(a[1])), fmaxf(fabsf(a[2]), fabsf(a[3])));
  am = blockMax256(am);
  if (threadIdx.x == 0) atomicMaxPosF(&sc[SC_AMAX_AO], am);
}

extern "C" void kernel_launch(void* const* d_in, const int* in_sizes, int n_in,
                              void* d_out, int out_size, void* d_ws, size_t ws_size,
                              hipStream_t stream) {
  const float* hidden = (const float*)d_in[0];
  const float* cosb   = (const float*)d_in[1];
  const float* sinb   = (const float*)d_in[2];
  const float* cachek = (const float*)d_in[3];
  const float* cachev = (const float*)d_in[4];
  const float* mask   = (const float*)d_in[5];
  const float* Wq     = (const float*)d_in[6];
  const float* bq     = (const float*)d_in[7];
  const float* Wk     = (const float*)d_in[8];
  const float* bk     = (const float*)d_in[9];
  const float* Wv     = (const float*)d_in[10];
  const float* bv     = (const float*)d_in[11];
  const float* Wo     = (const float*)d_in[12];
  float* out = (float*)d_out;

  char* base = (char*)d_ws;
  auto alloc = [&](size_t bytes) { char* p = base; base += (bytes + 255) & ~(size_t)255; return p; };

  float* SC  = (float*)alloc(64 * 4);
  float* SWq = (float*)alloc(HID * 4);
  float* SWk = (float*)alloc(NKV * HD * 4);
  float* SWv = (float*)alloc(NKV * HD * 4);
  float* SWo = (float*)alloc(HID * 4);
  u16* XI    = (u16*)alloc((size_t)S_LEN * HID * 2);
  u16* WQb   = (u16*)alloc((size_t)HID * HID * 2);
  u16* WKb   = (u16*)alloc((size_t)NKV * HD * HID * 2);
  u16* WVb   = (u16*)alloc((size_t)NKV * HD * HID * 2);
  u16* WOb   = (u16*)alloc((size_t)HID * HID * 2);
  float* QB  = (float*)alloc((size_t)S_LEN * HID * 4);
  float* KB  = (float*)alloc((size_t)S_LEN * NKV * HD * 4);
  float* VB  = (float*)alloc((size_t)S_LEN * NKV * HD * 4);
  u16* KCb   = (u16*)alloc((size_t)NKV * CL * HD * 2);
  u16* VCb   = (u16*)alloc((size_t)NKV * CL * HD * 2);
  u16* VT    = (u16*)alloc((size_t)NKV * HD * CL * 2);
  u16* QI    = (u16*)alloc((size_t)NH * S_LEN * HD * 2);
  float* PM  = (float*)alloc((size_t)KS * NH * S_LEN * 4);
  float* PL  = (float*)alloc((size_t)KS * NH * S_LEN * 4);
  float* MLm = (float*)alloc((size_t)NH * S_LEN * 4);
  float* MLl = (float*)alloc((size_t)NH * S_LEN * 4);
  float* AOp = (float*)alloc((size_t)KS * S_LEN * HID * 4);
  float* AO  = (float*)alloc((size_t)S_LEN * HID * 4);
  u16* AOi   = (u16*)alloc((size_t)S_LEN * HID * 2);

  k_init<<<1, 64, 0, stream>>>(SC);
  k_absmax4<<<1024, 256, 0, stream>>>(hidden, S_LEN * HID / 4, &SC[SC_AMAX_X]);
  k_absmax_cache<<<2048, 256, 0, stream>>>(cachek, &SC[SC_AMAX_CK], &SC[SC_AMAX_CK_TAIL]);
  k_absmax_cache<<<2048, 256, 0, stream>>>(cachev, &SC[SC_AMAX_CV], &SC[SC_AMAX_CV_TAIL]);
  k_quant_w_b<<<HID, 256, 0, stream>>>(Wq, WQb, SWq);
  k_quant_w_b<<<NKV * HD, 256, 0, stream>>>(Wk, WKb, SWk);
  k_quant_w_b<<<NKV * HD, 256, 0, stream>>>(Wv, WVb, SWv);
  k_quant_w_b<<<HID, 256, 0, stream>>>(Wo, WOb, SWo);
  k_combine1<<<1, 1, 0, stream>>>(SC);
  k_quant_act_b<<<1024, 256, 0, stream>>>(hidden, XI, S_LEN * HID / 4, SC, SC_SCALE_X);
  {
    dim3 gq(HID / 64, S_LEN / 64);
    k_gemm_q<<<gq, 256, 0, stream>>>(XI, WQb, SWq, bq, SC, SC_SCALE_X, QB, S_LEN, HID, HID);
    dim3 gk(NKV * HD / 64, S_LEN / 64);
    k_gemm_q<<<gk, 256, 0, stream>>>(XI, WKb, SWk, bk, SC, SC_SCALE_X, KB, S_LEN, NKV * HD, HID);
    k_gemm_q<<<gk, 256, 0, stream>>>(XI, WVb, SWv, bv, SC, SC_SCALE_X, VB, S_LEN, NKV * HD, HID);
  }
  k_rope<<<2048, 256, 0, stream>>>(QB, cosb, sinb, NH, &SC[SC_AMAX_Q]);
  k_rope<<<512, 256, 0, stream>>>(KB, cosb, sinb, NKV, &SC[SC_AMAX_K]);
  k_absmax4<<<256, 256, 0, stream>>>(VB, NKV * S_LEN * HD / 4, &SC[SC_AMAX_V]);
  k_combine2<<<1, 1, 0, stream>>>(SC);
  k_kvout<<<2048, 256, 0, stream>>>(KB, VB, out, SC);
  k_build_cache_b<<<4096, 256, 0, stream>>>(cachek, cachev, KB, VB, KCb, VCb, SC);
  k_transpose_v<<<NKV * (CL / 64) * (HD / 64), 256, 0, stream>>>(VCb, VT);
  k_quant_q<<<1024, 256, 0, stream>>>(QB, QI, SC);
  k_mattn1<<<NH * 8 * KS, 256, 0, stream>>>(QI, KCb, mask, SC, PM, PL);
  k_merge4<<<NH * S_LEN / 256, 256, 0, stream>>>(PM, PL, MLm, MLl, SC);
  k_combine3<<<1, 1, 0, stream>>>(SC);
  k_mattn2<<<NH * 8 * KS, 256, 0, stream>>>(QI, KCb, VT, mask, SC, MLm, MLl, AOp);
  k_combine_ao<<<1024, 256, 0, stream>>>(AOp, AO, SC);
  k_combine4<<<1, 1, 0, stream>>>(SC);
  k_quant_act_b<<<1024, 256, 0, stream>>>(AO, AOi, S_LEN * HID / 4, SC, SC_SCALE_O);
  {
    dim3 gq(HID / 64, S_LEN / 64);
    k_gemm_q<<<gq, 256, 0, stream>>>(AOi, WOb, SWo, nullptr, SC, SC_SCALE_O, out, S_LEN, HID, HID);
  }
  (void)in_sizes; (void)n_in; (void)out_size; (void)ws_size;
}

// Round 3
// 442.167 us; speedup vs baseline: 4.9789x; 1.1728x over previous
//
#include <hip/hip_runtime.h>
#include <math.h>

#define S_LEN 512
#define HID 2048
#define NH 16
#define NKV 4
#define HD 128
#define CL 8192
#define TAILN (CL - S_LEN)
#define KS 8                  // key partitions for attention passes
#define KCHUNK (CL / KS)      // 1024 keys per partition
#define INV_SQRT_HD 0.08838834764831845f

typedef unsigned short u16;
typedef __attribute__((ext_vector_type(8))) unsigned short u16x8;
typedef __attribute__((ext_vector_type(4))) unsigned short u16x4;
typedef __attribute__((ext_vector_type(8))) short bf16x8;
typedef __attribute__((ext_vector_type(4))) float f32x4;

enum {
  SC_AMAX_X = 0, SC_AMAX_CK, SC_AMAX_CK_TAIL, SC_AMAX_CV, SC_AMAX_CV_TAIL,
  SC_AMAX_Q, SC_AMAX_K, SC_AMAX_V, SC_AMAX_AO, SC_MIN_L,
  SC_SCALE_X, SC_SCALE_CK, SC_SCALE_CV, SC_SCALE_Q, SC_SCALE_KNEW,
  SC_SCALE_VNEW, SC_SCALE_KOUT, SC_SCALE_VOUT, SC_SCALE_P, SC_SCALE_O,
  SC_RSP, SC_PSV,
  SC_NUM
};

__device__ __forceinline__ float warpMax64(float v) {
  #pragma unroll
  for (int o = 32; o; o >>= 1) v = fmaxf(v, __shfl_down(v, o, 64));
  return v;
}
__device__ __forceinline__ float warpMin64(float v) {
  #pragma unroll
  for (int o = 32; o; o >>= 1) v = fminf(v, __shfl_down(v, o, 64));
  return v;
}
// requires blockDim.x == 256
__device__ __forceinline__ float blockMax256(float v) {
  __shared__ float sm_[4];
  __syncthreads();
  v = warpMax64(v);
  if ((threadIdx.x & 63) == 0) sm_[threadIdx.x >> 6] = v;
  __syncthreads();
  return fmaxf(fmaxf(sm_[0], sm_[1]), fmaxf(sm_[2], sm_[3]));
}
__device__ __forceinline__ float blockMin256(float v) {
  __shared__ float sn_[4];
  __syncthreads();
  v = warpMin64(v);
  if ((threadIdx.x & 63) == 0) sn_[threadIdx.x >> 6] = v;
  __syncthreads();
  return fminf(fminf(sn_[0], sn_[1]), fminf(sn_[2], sn_[3]));
}
__device__ __forceinline__ void atomicMaxPosF(float* a, float v) {
  atomicMax((unsigned int*)a, __float_as_uint(v));
}
__device__ __forceinline__ void atomicMinPosF(float* a, float v) {
  atomicMin((unsigned int*)a, __float_as_uint(v));
}
__device__ __forceinline__ float clampq(float q) {
  return fminf(fmaxf(q, -128.f), 127.f);
}
__device__ __forceinline__ u16 bf16bits(float f) {
  // exact for small integers (<= 8 significant bits)
  return (u16)(__float_as_uint(f) >> 16);
}

__global__ void k_init(float* sc) {
  int i = threadIdx.x;
  if (i < SC_NUM) sc[i] = (i == SC_MIN_L) ? INFINITY : 0.f;
}

__global__ __launch_bounds__(256) void k_absmax4(const float* __restrict__ x, int n4, float* slot) {
  float m = 0.f;
  const float4* x4 = (const float4*)x;
  for (int i = blockIdx.x * 256 + threadIdx.x; i < n4; i += gridDim.x * 256) {
    float4 v = x4[i];
    m = fmaxf(m, fmaxf(fmaxf(fabsf(v.x), fabsf(v.y)), fmaxf(fabsf(v.z), fabsf(v.w))));
  }
  m = blockMax256(m);
  if (threadIdx.x == 0) atomicMaxPosF(slot, m);
}

__global__ __launch_bounds__(256) void k_absmax_cache(const float* __restrict__ x, float* sfull, float* stail) {
  float mf = 0.f, mt = 0.f;
  const float4* x4 = (const float4*)x;
  const int n4 = NKV * CL * HD / 4;
  for (int i = blockIdx.x * 256 + threadIdx.x; i < n4; i += gridDim.x * 256) {
    float4 v = x4[i];
    float a = fmaxf(fmaxf(fabsf(v.x), fabsf(v.y)), fmaxf(fabsf(v.z), fabsf(v.w)));
    mf = fmaxf(mf, a);
    int t = (i >> 5) & (CL - 1);   // HD/4 = 32 float4 per row
    if (t >= S_LEN) mt = fmaxf(mt, a);
  }
  mf = blockMax256(mf);
  mt = blockMax256(mt);
  if (threadIdx.x == 0) { atomicMaxPosF(sfull, mf); atomicMaxPosF(stail, mt); }
}

// per-out-channel weight fake-quant -> bf16 integer codes + per-row scale. K == HID.
__global__ __launch_bounds__(256) void k_quant_w_b(const float* __restrict__ W, u16* __restrict__ Wb,
                                                   float* __restrict__ SW) {
  size_t base = (size_t)blockIdx.x * HID;
  const float4* w4 = (const float4*)(W + base);
  const int n4 = HID / 4;
  float am = 0.f;
  for (int i = threadIdx.x; i < n4; i += 256) {
    float4 v = w4[i];
    am = fmaxf(am, fmaxf(fmaxf(fabsf(v.x), fabsf(v.y)), fmaxf(fabsf(v.z), fabsf(v.w))));
  }
  am = blockMax256(am);
  float s = fmaxf(am, 1e-8f) / 127.f;
  if (threadIdx.x == 0) SW[blockIdx.x] = s;
  for (int i = threadIdx.x; i < n4; i += 256) {
    float4 v = w4[i];
    u16x4 o;
    o[0] = bf16bits(clampq(rintf(v.x / s)));
    o[1] = bf16bits(clampq(rintf(v.y / s)));
    o[2] = bf16bits(clampq(rintf(v.z / s)));
    o[3] = bf16bits(clampq(rintf(v.w / s)));
    *(u16x4*)(Wb + base + (size_t)i * 4) = o;
  }
}

// activation fake-quant -> bf16 integer codes, layout preserved
__global__ __launch_bounds__(256) void k_quant_act_b(const float* __restrict__ in, u16* __restrict__ outp,
                                                     int n4, const float* __restrict__ sc, int slot) {
  float s = sc[slot];
  const float4* i4 = (const float4*)in;
  for (int i = blockIdx.x * 256 + threadIdx.x; i < n4; i += gridDim.x * 256) {
    float4 v = i4[i];
    u16x4 o;
    o[0] = bf16bits(clampq(rintf(v.x / s)));
    o[1] = bf16bits(clampq(rintf(v.y / s)));
    o[2] = bf16bits(clampq(rintf(v.z / s)));
    o[3] = bf16bits(clampq(rintf(v.w / s)));
    *(u16x4*)(outp + (size_t)i * 4) = o;
  }
}

// QB f32 [S][NH*HD] -> QI bf16-int [NH][S][HD]
__global__ __launch_bounds__(256) void k_quant_q(const float* __restrict__ QB, u16* __restrict__ QI,
                                                 const float* __restrict__ sc) {
  int idx = blockIdx.x * 256 + threadIdx.x;   // S*NH*HD/4 = 262144
  float s = sc[SC_SCALE_Q];
  int e = idx * 4;
  int srow = e >> 11, rem = e & 2047;
  int h = rem >> 7, d = rem & 127;
  float4 v = *(const float4*)&QB[e];
  u16x4 o;
  o[0] = bf16bits(clampq(rintf(v.x / s)));
  o[1] = bf16bits(clampq(rintf(v.y / s)));
  o[2] = bf16bits(clampq(rintf(v.z / s)));
  o[3] = bf16bits(clampq(rintf(v.w / s)));
  *(u16x4*)(QI + ((size_t)h * S_LEN + srow) * HD + d) = o;
}

__global__ void k_combine1(float* sc) {
  sc[SC_SCALE_X]  = fmaxf(sc[SC_AMAX_X],  1e-8f) / 127.f;
  sc[SC_SCALE_CK] = fmaxf(sc[SC_AMAX_CK], 1e-8f) / 127.f;
  sc[SC_SCALE_CV] = fmaxf(sc[SC_AMAX_CV], 1e-8f) / 127.f;
}
__global__ void k_combine2(float* sc) {
  float sck = sc[SC_SCALE_CK], scv = sc[SC_SCALE_CV];
  float tqk = fminf(rintf(sc[SC_AMAX_CK_TAIL] / sck), 127.f) * sck;
  float tqv = fminf(rintf(sc[SC_AMAX_CV_TAIL] / scv), 127.f) * scv;
  sc[SC_SCALE_Q]    = fmaxf(sc[SC_AMAX_Q], 1e-8f) / 127.f;
  sc[SC_SCALE_KOUT] = fmaxf(sc[SC_AMAX_K], 1e-8f) / 127.f;
  sc[SC_SCALE_VOUT] = fmaxf(sc[SC_AMAX_V], 1e-8f) / 127.f;
  sc[SC_SCALE_KNEW] = fmaxf(fmaxf(tqk, sc[SC_AMAX_K]), 1e-8f) / 127.f;
  sc[SC_SCALE_VNEW] = fmaxf(fmaxf(tqv, sc[SC_AMAX_V]), 1e-8f) / 127.f;
}
__global__ void k_combine3(float* sc) {
  float sp = fmaxf(1.0f / sc[SC_MIN_L], 1e-8f) / 127.f;
  sc[SC_SCALE_P] = sp;
  sc[SC_RSP] = 1.0f / sp;
  sc[SC_PSV] = sp * sc[SC_SCALE_VNEW];
}
__global__ void k_combine4(float* sc) {
  sc[SC_SCALE_O] = fmaxf(sc[SC_AMAX_AO], 1e-8f) / 127.f;
}

// integer-domain MFMA GEMM: C[M,N] = (Aint[M,K] x Bint[N,K]^T) * (sx*SW[col]) + bias
// 64x64 tile, BK=64, 4 waves (2x2 of 32x32)
__global__ __launch_bounds__(256) void k_gemm_q(const u16* __restrict__ A, const u16* __restrict__ B,
                                                const float* __restrict__ SW, const float* __restrict__ bias,
                                                const float* __restrict__ sc, int sxslot,
                                                float* __restrict__ C, int M, int N, int K) {
  __shared__ u16 Al[64 * 64];
  __shared__ u16 Bl[64 * 64];
  int tid = threadIdx.x, lane = tid & 63, w = tid >> 6;
  int g = lane >> 4, c = lane & 15;
  int wy = w >> 1, wx = w & 1;
  int r0 = blockIdx.y * 64, c0 = blockIdx.x * 64;
  float sx = sc[sxslot];
  f32x4 acc[2][2] = {};
  for (int k0 = 0; k0 < K; k0 += 64) {
    __syncthreads();
    #pragma unroll
    for (int i = 0; i < 2; i++) {
      int b = tid + i * 256;
      int row = b >> 3, c8d = b & 7, c8s = c8d ^ (row & 7);
      *(u16x8*)(Al + row * 64 + c8d * 8) = *(const u16x8*)(A + (size_t)(r0 + row) * K + k0 + c8s * 8);
    }
    #pragma unroll
    for (int i = 0; i < 2; i++) {
      int b = tid + i * 256;
      int row = b >> 3, c8d = b & 7, c8s = c8d ^ (row & 7);
      *(u16x8*)(Bl + row * 64 + c8d * 8) = *(const u16x8*)(B + (size_t)(c0 + row) * K + k0 + c8s * 8);
    }
    __syncthreads();
    #pragma unroll
    for (int ks = 0; ks < 2; ks++) {
      bf16x8 af[2], bf[2];
      #pragma unroll
      for (int a = 0; a < 2; a++) {
        int row = wy * 32 + a * 16 + c;
        af[a] = *(const bf16x8*)(Al + row * 64 + (((4 * ks + g) ^ (row & 7)) * 8));
      }
      #pragma unroll
      for (int b = 0; b < 2; b++) {
        int row = wx * 32 + b * 16 + c;
        bf[b] = *(const bf16x8*)(Bl + row * 64 + (((4 * ks + g) ^ (row & 7)) * 8));
      }
      #pragma unroll
      for (int a = 0; a < 2; a++)
        #pragma unroll
        for (int b = 0; b < 2; b++)
          acc[a][b] = __builtin_amdgcn_mfma_f32_16x16x32_bf16(af[a], bf[b], acc[a][b], 0, 0, 0);
    }
  }
  #pragma unroll
  for (int a = 0; a < 2; a++)
    #pragma unroll
    for (int b = 0; b < 2; b++) {
      int col = c0 + wx * 32 + b * 16 + c;
      float sca = sx * SW[col];
      float bs = bias ? bias[col] : 0.f;
      #pragma unroll
      for (int r = 0; r < 4; r++) {
        int row = r0 + wy * 32 + a * 16 + 4 * g + r;
        C[(size_t)row * N + col] = acc[a][b][r] * sca + bs;
      }
    }
}

// in-place RoPE on [S, nheads*HD] + amax reduction
__global__ __launch_bounds__(256) void k_rope(float* __restrict__ B, const float* __restrict__ cosb,
                                              const float* __restrict__ sinb, int nheads,
                                              float* __restrict__ amax_slot) {
  int n = S_LEN * nheads * 64;
  int stride = nheads * HD;
  float am = 0.f;
  for (int idx = blockIdx.x * 256 + threadIdx.x; idx < n; idx += gridDim.x * 256) {
    int s = idx / (nheads * 64);
    int rem = idx - s * nheads * 64;
    int h = rem >> 6, d = rem & 63;
    float c1 = cosb[s * HD + d], s1 = sinb[s * HD + d];
    float c2 = cosb[s * HD + d + 64], s2 = sinb[s * HD + d + 64];
    float* p = &B[(size_t)s * stride + h * HD + d];
    float x1 = p[0], x2 = p[64];
    float y1 = x1 * c1 - x2 * s1;
    float y2 = x2 * c2 + x1 * s2;
    p[0] = y1; p[64] = y2;
    am = fmaxf(am, fmaxf(fabsf(y1), fabsf(y2)));
  }
  am = blockMax256(am);
  if (threadIdx.x == 0) atomicMaxPosF(amax_slot, am);
}

// k_out / v_out (fq of fresh k,v) into d_out after the main output
__global__ __launch_bounds__(256) void k_kvout(const float* __restrict__ KB, const float* __restrict__ VB,
                                               float* __restrict__ dout, const float* __restrict__ sc) {
  const int n1 = NKV * S_LEN * HD;
  float sk = sc[SC_SCALE_KOUT], sv = sc[SC_SCALE_VOUT];
  for (int i = blockIdx.x * 256 + threadIdx.x; i < 2 * n1; i += gridDim.x * 256) {
    int isv = i >= n1;
    int j = i - isv * n1;
    int kvh = j / (S_LEN * HD);
    int rem = j - kvh * S_LEN * HD;
    int s = rem / HD, d = rem - s * HD;
    float x = (isv ? VB : KB)[(size_t)s * (NKV * HD) + kvh * HD + d];
    float ss = isv ? sv : sk;
    dout[(size_t)S_LEN * HID + i] = clampq(rintf(x / ss)) * ss;
  }
}

// build updated caches as bf16 INTEGER codes (value = int * SCALE_{K,V}NEW)
__global__ __launch_bounds__(256) void k_build_cache_b(const float* __restrict__ ck, const float* __restrict__ cv,
                                                       const float* __restrict__ KB, const float* __restrict__ VB,
                                                       u16* __restrict__ KCb, u16* __restrict__ VCb,
                                                       const float* __restrict__ sc) {
  const int n1 = NKV * CL * HD;
  float sck = sc[SC_SCALE_CK], scv = sc[SC_SCALE_CV];
  float skn = sc[SC_SCALE_KNEW], svn = sc[SC_SCALE_VNEW];
  for (int i = blockIdx.x * 256 + threadIdx.x; i < 2 * n1; i += gridDim.x * 256) {
    int isv = i >= n1;
    int j = i - isv * n1;
    int kvh = j / (CL * HD);
    int rem = j - kvh * CL * HD;
    int t = rem / HD, d = rem - t * HD;
    float s1 = isv ? scv : sck, s2 = isv ? svn : skn;
    float outi;
    if (t < TAILN) {
      float x = (isv ? cv : ck)[(size_t)kvh * CL * HD + (size_t)(t + S_LEN) * HD + d];
      float v1 = clampq(rintf(x / s1)) * s1;
      outi = clampq(rintf(v1 / s2));
    } else {
      float x = (isv ? VB : KB)[(size_t)(t - TAILN) * (NKV * HD) + kvh * HD + d];
      outi = clampq(rintf(x / s2));
    }
    (isv ? VCb : KCb)[j] = bf16bits(outi);
  }
}

// VCb [NKV][CL][HD] -> VT [NKV][HD][CL]
__global__ __launch_bounds__(256) void k_transpose_v(const u16* __restrict__ VCb, u16* __restrict__ VT) {
  __shared__ u16 T[64][72];
  int bid = blockIdx.x;
  int kv = bid >> 8, rem = bid & 255, tb = rem >> 1, db = rem & 1;
  int tid = threadIdx.x;
  int r = tid >> 3, cb = tid & 7;
  #pragma unroll
  for (int i = 0; i < 2; i++) {
    int row = r + i * 32;
    u16x8 v = *(const u16x8*)(VCb + ((size_t)kv * CL + tb * 64 + row) * HD + db * 64 + cb * 8);
    *(u16x8*)&T[row][cb * 8] = v;
  }
  __syncthreads();
  #pragma unroll
  for (int i = 0; i < 2; i++) {
    int drow = r + i * 32;
    u16x8 v;
    #pragma unroll
    for (int j = 0; j < 8; j++) v[j] = T[cb * 8 + j][drow];
    *(u16x8*)(VT + ((size_t)kv * HD + db * 64 + drow) * CL + tb * 64 + cb * 8) = v;
  }
}

// pass 1: MFMA QK^T, batched per-tile softmax stats (independent exps), shfl merge.
// grid = NH * 8 * KS
__global__ __launch_bounds__(256) void k_mattn1(const u16* __restrict__ QI, const u16* __restrict__ KCb,
                                                const float* __restrict__ mask, const float* __restrict__ sc,
                                                float* __restrict__ PM, float* __restrict__ PL) {
  __shared__ u16 Kl[64 * HD];        // 16 KB
  __shared__ float Ml[64][65];       // 16.6 KB mask tile
  int bid = blockIdx.x;
  int kc = bid & (KS - 1), qb = (bid >> 3) & 7, h = bid >> 6, kv = h >> 2;
  int tid = threadIdx.x, lane = tid & 63, w = tid >> 6, g = lane >> 4, c = lane & 15;
  float sscale = sc[SC_SCALE_Q] * sc[SC_SCALE_KNEW] * INV_SQRT_HD;
  int q0 = qb * 64 + w * 16;
  bf16x8 qf[4];
  {
    const u16* qrow = QI + ((size_t)h * S_LEN + q0 + c) * HD + g * 8;
    #pragma unroll
    for (int ds = 0; ds < 4; ds++) qf[ds] = *(const bf16x8*)(qrow + 32 * ds);
  }
  float m[4], l[4];
  #pragma unroll
  for (int r = 0; r < 4; r++) { m[r] = -INFINITY; l[r] = 0.f; }
  int wrow = w * 16 + 4 * g;              // block-relative q row base for this lane
  int qlane = q0 + 4 * g;
  int kbase0 = kc * KCHUNK;
  const u16* Kg = KCb + (size_t)kv * CL * HD;
  const float* maskb = mask + (size_t)qb * 64 * CL;
  for (int kb = 0; kb < KCHUNK; kb += 64) {
    int kbase = kbase0 + kb;
    __syncthreads();
    #pragma unroll
    for (int i = 0; i < 4; i++) {      // stage K tile [64][128] swizzled
      int b = tid + i * 256;
      int row = b >> 4, c8d = b & 15, c8s = c8d ^ (row & 7);
      *(u16x8*)(Kl + row * HD + c8d * 8) = *(const u16x8*)(Kg + (size_t)(kbase + row) * HD + c8s * 8);
    }
    #pragma unroll
    for (int i = 0; i < 4; i++) {      // stage mask tile [64][64] f32
      int b = tid + i * 256;
      int row = b >> 4, c4 = (b & 15) << 2;
      float4 v = *(const float4*)&maskb[(size_t)row * CL + kbase + c4];
      Ml[row][c4] = v.x; Ml[row][c4 + 1] = v.y; Ml[row][c4 + 2] = v.z; Ml[row][c4 + 3] = v.w;
    }
    __syncthreads();
    f32x4 sc4[4];                      // [kf] -> 4 rows' scores at key kf*16+c
    #pragma unroll
    for (int kf = 0; kf < 4; kf++) {
      f32x4 s4 = {0.f, 0.f, 0.f, 0.f};
      int krow = kf * 16 + c;
      #pragma unroll
      for (int ds = 0; ds < 4; ds++) {
        bf16x8 kf8 = *(const bf16x8*)(Kl + krow * HD + (((4 * ds + g) ^ (krow & 7)) * 8));
        s4 = __builtin_amdgcn_mfma_f32_16x16x32_bf16(qf[ds], kf8, s4, 0, 0, 0);
      }
      sc4[kf] = s4;
    }
    #pragma unroll
    for (int r = 0; r < 4; r++) {
      float v0 = fmaf(sc4[0][r], sscale, Ml[wrow + r][c]);
      float v1 = fmaf(sc4[1][r], sscale, Ml[wrow + r][16 + c]);
      float v2 = fmaf(sc4[2][r], sscale, Ml[wrow + r][32 + c]);
      float v3 = fmaf(sc4[3][r], sscale, Ml[wrow + r][48 + c]);
      float tmax = fmaxf(fmaxf(v0, v1), fmaxf(v2, v3));
      float nm = fmaxf(m[r], tmax);
      float e0 = __expf(v0 - nm), e1 = __expf(v1 - nm);
      float e2 = __expf(v2 - nm), e3 = __expf(v3 - nm);
      float f = __expf(m[r] - nm);     // == 1 when max unchanged; 0 first tile
      l[r] = fmaf(l[r], f, (e0 + e1) + (e2 + e3));
      m[r] = nm;
    }
  }
  #pragma unroll
  for (int r = 0; r < 4; r++) {
    #pragma unroll
    for (int off = 1; off < 16; off <<= 1) {
      float om = __shfl_xor(m[r], off, 64);
      float ol = __shfl_xor(l[r], off, 64);
      float nm = fmaxf(m[r], om);
      l[r] = l[r] * __expf(m[r] - nm) + ol * __expf(om - nm);
      m[r] = nm;
    }
  }
  if (c == 0) {
    size_t base = ((size_t)kc * NH + h) * S_LEN + qlane;
    #pragma unroll
    for (int r = 0; r < 4; r++) { PM[base + r] = m[r]; PL[base + r] = l[r]; }
  }
}

__global__ __launch_bounds__(256) void k_merge4(const float* __restrict__ PM, const float* __restrict__ PL,
                                                float* __restrict__ MLm, float* __restrict__ MLl, float* sc) {
  int idx = blockIdx.x * 256 + threadIdx.x;   // NH*S_LEN = 8192
  const int st = NH * S_LEN;
  float m = PM[idx];
  #pragma unroll
  for (int p = 1; p < KS; p++) m = fmaxf(m, PM[p * st + idx]);
  float l = 0.f;
  #pragma unroll
  for (int p = 0; p < KS; p++) l += PL[p * st + idx] * __expf(PM[p * st + idx] - m);
  MLm[idx] = m; MLl[idx] = l;
  float lm = blockMin256(l);
  if (threadIdx.x == 0) atomicMinPosF(&sc[SC_MIN_L], lm);
}

// pass 2: MFMA QK^T (bit-identical), P quant via LDS, MFMA PV. grid = NH*8*KS
__global__ __launch_bounds__(256) void k_mattn2(const u16* __restrict__ QI, const u16* __restrict__ KCb,
                                                const u16* __restrict__ VT, const float* __restrict__ mask,
                                                const float* __restrict__ sc, const float* __restrict__ MLm,
                                                const float* __restrict__ MLl, float* __restrict__ AOp) {
  __shared__ u16 Kl[64 * HD];      // 16KB, swizzled row-major [key][d]
  __shared__ u16 Vl[HD * 64];      // 16KB, swizzled row-major [d][key]
  __shared__ u16 Pl[4 * 16 * 64];  // 8KB, per-wave [q][key], swizzled
  int bid = blockIdx.x;
  int kc = bid & (KS - 1), qb = (bid >> 3) & 7, h = bid >> 6, kv = h >> 2;
  int tid = threadIdx.x, lane = tid & 63, w = tid >> 6, g = lane >> 4, c = lane & 15;
  float sscale = sc[SC_SCALE_Q] * sc[SC_SCALE_KNEW] * INV_SQRT_HD;
  float rsp = sc[SC_RSP], psv = sc[SC_PSV];
  int q0 = qb * 64 + w * 16;
  bf16x8 qf[4];
  {
    const u16* qrow = QI + ((size_t)h * S_LEN + q0 + c) * HD + g * 8;
    #pragma unroll
    for (int ds = 0; ds < 4; ds++) qf[ds] = *(const bf16x8*)(qrow + 32 * ds);
  }
  int qlane = q0 + 4 * g;
  float mreg[4], invl[4];
  #pragma unroll
  for (int r = 0; r < 4; r++) {
    mreg[r] = MLm[h * S_LEN + qlane + r];
    invl[r] = 1.0f / MLl[h * S_LEN + qlane + r];
  }
  f32x4 acc[8] = {};
  const u16* Kg = KCb + (size_t)kv * CL * HD;
  const u16* Vg = VT + (size_t)kv * HD * CL;
  int kbase0 = kc * KCHUNK;
  u16* Pw = Pl + w * 1024;
  for (int kb = 0; kb < KCHUNK; kb += 64) {
    int kbase = kbase0 + kb;
    __syncthreads();
    #pragma unroll
    for (int i = 0; i < 4; i++) {    // stage K chunk [64][128]
      int b = tid + i * 256;
      int row = b >> 4, c8d = b & 15, c8s = c8d ^ (row & 7);
      *(u16x8*)(Kl + row * HD + c8d * 8) = *(const u16x8*)(Kg + (size_t)(kbase + row) * HD + c8s * 8);
    }
    #pragma unroll
    for (int i = 0; i < 4; i++) {    // stage V^T chunk [128][64]
      int b = tid + i * 256;
      int row = b >> 3, c8d = b & 7, c8s = c8d ^ (row & 7);
      *(u16x8*)(Vl + row * 64 + c8d * 8) = *(const u16x8*)(Vg + (size_t)row * CL + kbase + c8s * 8);
    }
    __syncthreads();
    // QK^T + softmax + P quant (identical arithmetic to pass 1)
    #pragma unroll
    for (int kf = 0; kf < 4; kf++) {
      f32x4 s4 = {0.f, 0.f, 0.f, 0.f};
      int krow = kf * 16 + c;
      #pragma unroll
      for (int ds = 0; ds < 4; ds++) {
        bf16x8 kf8 = *(const bf16x8*)(Kl + krow * HD + (((4 * ds + g) ^ (krow & 7)) * 8));
        s4 = __builtin_amdgcn_mfma_f32_16x16x32_bf16(qf[ds], kf8, s4, 0, 0, 0);
      }
      int key = kbase + kf * 16 + c;
      #pragma unroll
      for (int r = 0; r < 4; r++) {
        float v = fmaf(s4[r], sscale, mask[(size_t)(qlane + r) * CL + key]);
        float p = __expf(v - mreg[r]) * invl[r];
        float pi = fminf(rintf(p * rsp), 127.f);
        int prow = 4 * g + r, pcol = kf * 16 + c;
        Pw[prow * 64 + (pcol ^ ((prow & 7) << 3))] = bf16bits(pi);
      }
    }
    __syncthreads();
    // PV
    bf16x8 pa[2];
    #pragma unroll
    for (int s = 0; s < 2; s++)
      pa[s] = *(const bf16x8*)(Pw + c * 64 + ((32 * s + 8 * g) ^ ((c & 7) << 3)));
    #pragma unroll
    for (int dt = 0; dt < 8; dt++) {
      #pragma unroll
      for (int s = 0; s < 2; s++) {
        int drow = dt * 16 + c;
        bf16x8 vf = *(const bf16x8*)(Vl + drow * 64 + (((4 * s + g) ^ (drow & 7)) * 8));
        acc[dt] = __builtin_amdgcn_mfma_f32_16x16x32_bf16(pa[s], vf, acc[dt], 0, 0, 0);
      }
    }
  }
  float* outp = AOp + (size_t)kc * S_LEN * HID;
  #pragma unroll
  for (int dt = 0; dt < 8; dt++)
    #pragma unroll
    for (int r = 0; r < 4; r++)
      outp[(size_t)(qlane + r) * HID + h * HD + dt * 16 + c] = acc[dt][r] * psv;
}

__global__ __launch_bounds__(256) void k_combine_ao(const float* __restrict__ AOp, float* __restrict__ AO,
                                                    float* sc) {
  int idx = blockIdx.x * 256 + threadIdx.x;   // S*HID/4 = 262144
  const int st = S_LEN * HID / 4;
  const f32x4* p4 = (const f32x4*)AOp;
  f32x4 a = p4[idx];
  #pragma unroll
  for (int p = 1; p < KS; p++) {
    f32x4 b = p4[p * st + idx];
    a = a + b;
  }
  *((f32x4*)AO + idx) = a;
  float am = fmaxf(fmaxf(fabsf(a[0]), fabsf(a[1])), fmaxf(fabsf(a[2]), fabsf(a[3])));
  am = blockMax256(am);
  if (threadIdx.x == 0) atomicMaxPosF(&sc[SC_AMAX_AO], am);
}

extern "C" void kernel_launch(void* const* d_in, const int* in_sizes, int n_in,
                              void* d_out, int out_size, void* d_ws, size_t ws_size,
                              hipStream_t stream) {
  const float* hidden = (const float*)d_in[0];
  const float* cosb   = (const float*)d_in[1];
  const float* sinb   = (const float*)d_in[2];
  const float* cachek = (const float*)d_in[3];
  const float* cachev = (const float*)d_in[4];
  const float* mask   = (const float*)d_in[5];
  const float* Wq     = (const float*)d_in[6];
  const float* bq     = (const float*)d_in[7];
  const float* Wk     = (const float*)d_in[8];
  const float* bk     = (const float*)d_in[9];
  const float* Wv     = (const float*)d_in[10];
  const float* bv     = (const float*)d_in[11];
  const float* Wo     = (const float*)d_in[12];
  float* out = (float*)d_out;

  char* base = (char*)d_ws;
  auto alloc = [&](size_t bytes) { char* p = base; base += (bytes + 255) & ~(size_t)255; return p; };

  float* SC  = (float*)alloc(64 * 4);
  float* SWq = (float*)alloc(HID * 4);
  float* SWk = (float*)alloc(NKV * HD * 4);
  float* SWv = (float*)alloc(NKV * HD * 4);
  float* SWo = (float*)alloc(HID * 4);
  u16* XI    = (u16*)alloc((size_t)S_LEN * HID * 2);
  u16* WQb   = (u16*)alloc((size_t)HID * HID * 2);
  u16* WKb   = (u16*)alloc((size_t)NKV * HD * HID * 2);
  u16* WVb   = (u16*)alloc((size_t)NKV * HD * HID * 2);
  u16* WOb   = (u16*)alloc((size_t)HID * HID * 2);
  float* QB  = (float*)alloc((size_t)S_LEN * HID * 4);
  float* KB  = (float*)alloc((size_t)S_LEN * NKV * HD * 4);
  float* VB  = (float*)alloc((size_t)S_LEN * NKV * HD * 4);
  u16* KCb   = (u16*)alloc((size_t)NKV * CL * HD * 2);
  u16* VCb   = (u16*)alloc((size_t)NKV * CL * HD * 2);
  u16* VT    = (u16*)alloc((size_t)NKV * HD * CL * 2);
  u16* QI    = (u16*)alloc((size_t)NH * S_LEN * HD * 2);
  float* PM  = (float*)alloc((size_t)KS * NH * S_LEN * 4);
  float* PL  = (float*)alloc((size_t)KS * NH * S_LEN * 4);
  float* MLm = (float*)alloc((size_t)NH * S_LEN * 4);
  float* MLl = (float*)alloc((size_t)NH * S_LEN * 4);
  float* AOp = (float*)alloc((size_t)KS * S_LEN * HID * 4);
  float* AO  = (float*)alloc((size_t)S_LEN * HID * 4);
  u16* AOi   = (u16*)alloc((size_t)S_LEN * HID * 2);

  k_init<<<1, 64, 0, stream>>>(SC);
  k_absmax4<<<1024, 256, 0, stream>>>(hidden, S_LEN * HID / 4, &SC[SC_AMAX_X]);
  k_absmax_cache<<<2048, 256, 0, stream>>>(cachek, &SC[SC_AMAX_CK], &SC[SC_AMAX_CK_TAIL]);
  k_absmax_cache<<<2048, 256, 0, stream>>>(cachev, &SC[SC_AMAX_CV], &SC[SC_AMAX_CV_TAIL]);
  k_quant_w_b<<<HID, 256, 0, stream>>>(Wq, WQb, SWq);
  k_quant_w_b<<<NKV * HD, 256, 0, stream>>>(Wk, WKb, SWk);
  k_quant_w_b<<<NKV * HD, 256, 0, stream>>>(Wv, WVb, SWv);
  k_quant_w_b<<<HID, 256, 0, stream>>>(Wo, WOb, SWo);
  k_combine1<<<1, 1, 0, stream>>>(SC);
  k_quant_act_b<<<1024, 256, 0, stream>>>(hidden, XI, S_LEN * HID / 4, SC, SC_SCALE_X);
  {
    dim3 gq(HID / 64, S_LEN / 64);
    k_gemm_q<<<gq, 256, 0, stream>>>(XI, WQb, SWq, bq, SC, SC_SCALE_X, QB, S_LEN, HID, HID);
    dim3 gk(NKV * HD / 64, S_LEN / 64);
    k_gemm_q<<<gk, 256, 0, stream>>>(XI, WKb, SWk, bk, SC, SC_SCALE_X, KB, S_LEN, NKV * HD, HID);
    k_gemm_q<<<gk, 256, 0, stream>>>(XI, WVb, SWv, bv, SC, SC_SCALE_X, VB, S_LEN, NKV * HD, HID);
  }
  k_rope<<<2048, 256, 0, stream>>>(QB, cosb, sinb, NH, &SC[SC_AMAX_Q]);
  k_rope<<<512, 256, 0, stream>>>(KB, cosb, sinb, NKV, &SC[SC_AMAX_K]);
  k_absmax4<<<256, 256, 0, stream>>>(VB, NKV * S_LEN * HD / 4, &SC[SC_AMAX_V]);
  k_combine2<<<1, 1, 0, stream>>>(SC);
  k_kvout<<<2048, 256, 0, stream>>>(KB, VB, out, SC);
  k_build_cache_b<<<4096, 256, 0, stream>>>(cachek, cachev, KB, VB, KCb, VCb, SC);
  k_transpose_v<<<NKV * (CL / 64) * (HD / 64), 256, 0, stream>>>(VCb, VT);
  k_quant_q<<<1024, 256, 0, stream>>>(QB, QI, SC);
  k_mattn1<<<NH * 8 * KS, 256, 0, stream>>>(QI, KCb, mask, SC, PM, PL);
  k_merge4<<<NH * S_LEN / 256, 256, 0, stream>>>(PM, PL, MLm, MLl, SC);
  k_combine3<<<1, 1, 0, stream>>>(SC);
  k_mattn2<<<NH * 8 * KS, 256, 0, stream>>>(QI, KCb, VT, mask, SC, MLm, MLl, AOp);
  k_combine_ao<<<1024, 256, 0, stream>>>(AOp, AO, SC);
  k_combine4<<<1, 1, 0, stream>>>(SC);
  k_quant_act_b<<<1024, 256, 0, stream>>>(AO, AOi, S_LEN * HID / 4, SC, SC_SCALE_O);
  {
    dim3 gq(HID / 64, S_LEN / 64);
    k_gemm_q<<<gq, 256, 0, stream>>>(AOi, WOb, SWo, nullptr, SC, SC_SCALE_O, out, S_LEN, HID, HID);
  }
  (void)in_sizes; (void)n_in; (void)out_size; (void)ws_size;
}

// Round 4
// 368.425 us; speedup vs baseline: 5.9755x; 1.2002x over previous
//
#include <hip/hip_runtime.h>
#include <math.h>

#define S_LEN 512
#define HID 2048
#define NH 16
#define NKV 4
#define HD 128
#define CL 8192
#define TAILN (CL - S_LEN)
#define KS1 16                 // key partitions pass 1
#define KCH1 (CL / KS1)        // 512
#define KS2 8                  // key partitions pass 2
#define KCH2 (CL / KS2)        // 1024
#define INV_SQRT_HD 0.08838834764831845f

typedef unsigned short u16;
typedef __attribute__((ext_vector_type(8))) unsigned short u16x8;
typedef __attribute__((ext_vector_type(4))) unsigned short u16x4;
typedef __attribute__((ext_vector_type(8))) short bf16x8;
typedef __attribute__((ext_vector_type(4))) float f32x4;

enum {
  SC_AMAX_X = 0, SC_AMAX_CK, SC_AMAX_CK_TAIL, SC_AMAX_CV, SC_AMAX_CV_TAIL,
  SC_AMAX_Q, SC_AMAX_K, SC_AMAX_V, SC_AMAX_AO, SC_MIN_L,
  SC_NUM
};

__device__ __forceinline__ float warpMax64(float v) {
  #pragma unroll
  for (int o = 32; o; o >>= 1) v = fmaxf(v, __shfl_down(v, o, 64));
  return v;
}
__device__ __forceinline__ float warpMin64(float v) {
  #pragma unroll
  for (int o = 32; o; o >>= 1) v = fminf(v, __shfl_down(v, o, 64));
  return v;
}
// requires blockDim.x == 256
__device__ __forceinline__ float blockMax256(float v) {
  __shared__ float sm_[4];
  __syncthreads();
  v = warpMax64(v);
  if ((threadIdx.x & 63) == 0) sm_[threadIdx.x >> 6] = v;
  __syncthreads();
  return fmaxf(fmaxf(sm_[0], sm_[1]), fmaxf(sm_[2], sm_[3]));
}
__device__ __forceinline__ float blockMin256(float v) {
  __shared__ float sn_[4];
  __syncthreads();
  v = warpMin64(v);
  if ((threadIdx.x & 63) == 0) sn_[threadIdx.x >> 6] = v;
  __syncthreads();
  return fminf(fminf(sn_[0], sn_[1]), fminf(sn_[2], sn_[3]));
}
__device__ __forceinline__ void atomicMaxPosF(float* a, float v) {
  atomicMax((unsigned int*)a, __float_as_uint(v));
}
__device__ __forceinline__ void atomicMinPosF(float* a, float v) {
  atomicMin((unsigned int*)a, __float_as_uint(v));
}
__device__ __forceinline__ float clampq(float q) {
  return fminf(fmaxf(q, -128.f), 127.f);
}
__device__ __forceinline__ u16 bf16bits(float f) {
  return (u16)(__float_as_uint(f) >> 16);   // exact for small integers
}
__device__ __forceinline__ float mk_scale(float am) {
  return fmaxf(am, 1e-8f) / 127.f;
}
__device__ __forceinline__ void gl2lds16(const u16* g, u16* l) {
  __builtin_amdgcn_global_load_lds((const __attribute__((address_space(1))) void*)g,
                                   (__attribute__((address_space(3))) void*)l, 16, 0, 0);
}

__global__ void k_init(float* sc) {
  int i = threadIdx.x;
  if (i < SC_NUM) sc[i] = (i == SC_MIN_L) ? INFINITY : 0.f;
}

__global__ __launch_bounds__(256) void k_absmax4(const float* __restrict__ x, int n4, float* slot) {
  float m = 0.f;
  const float4* x4 = (const float4*)x;
  for (int i = blockIdx.x * 256 + threadIdx.x; i < n4; i += gridDim.x * 256) {
    float4 v = x4[i];
    m = fmaxf(m, fmaxf(fmaxf(fabsf(v.x), fabsf(v.y)), fmaxf(fabsf(v.z), fabsf(v.w))));
  }
  m = blockMax256(m);
  if (threadIdx.x == 0) atomicMaxPosF(slot, m);
}

// both caches, full + tail amax, one launch
__global__ __launch_bounds__(256) void k_absmax_caches(const float* __restrict__ ck,
                                                       const float* __restrict__ cv, float* sc) {
  const int n4 = NKV * CL * HD / 4;
  float mkf = 0.f, mkt = 0.f, mvf = 0.f, mvt = 0.f;
  for (int i = blockIdx.x * 256 + threadIdx.x; i < 2 * n4; i += gridDim.x * 256) {
    int isv = i >= n4;
    int j = i - isv * n4;
    float4 v = ((const float4*)(isv ? cv : ck))[j];
    float a = fmaxf(fmaxf(fabsf(v.x), fabsf(v.y)), fmaxf(fabsf(v.z), fabsf(v.w)));
    int t = (j >> 5) & (CL - 1);
    if (isv) { mvf = fmaxf(mvf, a); if (t >= S_LEN) mvt = fmaxf(mvt, a); }
    else     { mkf = fmaxf(mkf, a); if (t >= S_LEN) mkt = fmaxf(mkt, a); }
  }
  mkf = blockMax256(mkf); mkt = blockMax256(mkt);
  mvf = blockMax256(mvf); mvt = blockMax256(mvt);
  if (threadIdx.x == 0) {
    atomicMaxPosF(&sc[SC_AMAX_CK], mkf); atomicMaxPosF(&sc[SC_AMAX_CK_TAIL], mkt);
    atomicMaxPosF(&sc[SC_AMAX_CV], mvf); atomicMaxPosF(&sc[SC_AMAX_CV_TAIL], mvt);
  }
}

// all 4 weight matrices, one block per output row
__global__ __launch_bounds__(256) void k_quant_w_all(const float* __restrict__ Wq, const float* __restrict__ Wk,
                                                     const float* __restrict__ Wv, const float* __restrict__ Wo,
                                                     u16* __restrict__ WQb, u16* __restrict__ WKb,
                                                     u16* __restrict__ WVb, u16* __restrict__ WOb,
                                                     float* __restrict__ SWq, float* __restrict__ SWk,
                                                     float* __restrict__ SWv, float* __restrict__ SWo) {
  int r = blockIdx.x;
  const float* W; u16* Wb; float* SW; int row;
  if (r < 2048)      { W = Wq; Wb = WQb; SW = SWq; row = r; }
  else if (r < 2560) { W = Wk; Wb = WKb; SW = SWk; row = r - 2048; }
  else if (r < 3072) { W = Wv; Wb = WVb; SW = SWv; row = r - 2560; }
  else               { W = Wo; Wb = WOb; SW = SWo; row = r - 3072; }
  size_t base = (size_t)row * HID;
  const float4* w4 = (const float4*)(W + base);
  const int n4 = HID / 4;
  float am = 0.f;
  for (int i = threadIdx.x; i < n4; i += 256) {
    float4 v = w4[i];
    am = fmaxf(am, fmaxf(fmaxf(fabsf(v.x), fabsf(v.y)), fmaxf(fabsf(v.z), fabsf(v.w))));
  }
  am = blockMax256(am);
  float s = fmaxf(am, 1e-8f) / 127.f;
  if (threadIdx.x == 0) SW[row] = s;
  for (int i = threadIdx.x; i < n4; i += 256) {
    float4 v = w4[i];
    u16x4 o;
    o[0] = bf16bits(clampq(rintf(v.x / s)));
    o[1] = bf16bits(clampq(rintf(v.y / s)));
    o[2] = bf16bits(clampq(rintf(v.z / s)));
    o[3] = bf16bits(clampq(rintf(v.w / s)));
    *(u16x4*)(Wb + base + (size_t)i * 4) = o;
  }
}

// activation fake-quant -> bf16 integer codes; scale computed inline from amax slot
__global__ __launch_bounds__(256) void k_quant_act_b(const float* __restrict__ in, u16* __restrict__ outp,
                                                     int n4, const float* __restrict__ sc, int axslot) {
  float s = mk_scale(sc[axslot]);
  const float4* i4 = (const float4*)in;
  for (int i = blockIdx.x * 256 + threadIdx.x; i < n4; i += gridDim.x * 256) {
    float4 v = i4[i];
    u16x4 o;
    o[0] = bf16bits(clampq(rintf(v.x / s)));
    o[1] = bf16bits(clampq(rintf(v.y / s)));
    o[2] = bf16bits(clampq(rintf(v.z / s)));
    o[3] = bf16bits(clampq(rintf(v.w / s)));
    *(u16x4*)(outp + (size_t)i * 4) = o;
  }
}

// QB f32 [S][NH*HD] -> QI bf16-int [NH][S][HD]
__global__ __launch_bounds__(256) void k_quant_q(const float* __restrict__ QB, u16* __restrict__ QI,
                                                 const float* __restrict__ sc) {
  int idx = blockIdx.x * 256 + threadIdx.x;
  float s = mk_scale(sc[SC_AMAX_Q]);
  int e = idx * 4;
  int srow = e >> 11, rem = e & 2047;
  int h = rem >> 7, d = rem & 127;
  float4 v = *(const float4*)&QB[e];
  u16x4 o;
  o[0] = bf16bits(clampq(rintf(v.x / s)));
  o[1] = bf16bits(clampq(rintf(v.y / s)));
  o[2] = bf16bits(clampq(rintf(v.z / s)));
  o[3] = bf16bits(clampq(rintf(v.w / s)));
  *(u16x4*)(QI + ((size_t)h * S_LEN + srow) * HD + d) = o;
}

// fused QKV GEMM: C = (XI x W^T) * (sx*SW[col]) + bias; 64x64 tiles, grid (48, 8)
__global__ __launch_bounds__(256) void k_gemm_qkv(const u16* __restrict__ A,
                                                  const u16* __restrict__ WQb, const u16* __restrict__ WKb,
                                                  const u16* __restrict__ WVb,
                                                  const float* __restrict__ SWq, const float* __restrict__ SWk,
                                                  const float* __restrict__ SWv,
                                                  const float* __restrict__ bq, const float* __restrict__ bk,
                                                  const float* __restrict__ bv,
                                                  const float* __restrict__ sc,
                                                  float* __restrict__ QB, float* __restrict__ KB,
                                                  float* __restrict__ VB) {
  __shared__ u16 Al[64 * 64];
  __shared__ u16 Bl[64 * 64];
  int bx = blockIdx.x;
  const u16* B; const float* SW; const float* bias; float* C; int N, c0;
  if (bx < 32)      { B = WQb; SW = SWq; bias = bq; C = QB; N = HID; c0 = bx * 64; }
  else if (bx < 40) { B = WKb; SW = SWk; bias = bk; C = KB; N = NKV * HD; c0 = (bx - 32) * 64; }
  else              { B = WVb; SW = SWv; bias = bv; C = VB; N = NKV * HD; c0 = (bx - 40) * 64; }
  int tid = threadIdx.x, lane = tid & 63, w = tid >> 6;
  int g = lane >> 4, c = lane & 15;
  int wy = w >> 1, wx = w & 1;
  int r0 = blockIdx.y * 64;
  float sx = mk_scale(sc[SC_AMAX_X]);
  f32x4 acc[2][2] = {};
  for (int k0 = 0; k0 < HID; k0 += 64) {
    __syncthreads();
    #pragma unroll
    for (int i = 0; i < 2; i++) {
      int b = tid + i * 256;
      int row = b >> 3, c8d = b & 7, c8s = c8d ^ (row & 7);
      gl2lds16(A + (size_t)(r0 + row) * HID + k0 + c8s * 8, Al + b * 8);
    }
    #pragma unroll
    for (int i = 0; i < 2; i++) {
      int b = tid + i * 256;
      int row = b >> 3, c8d = b & 7, c8s = c8d ^ (row & 7);
      gl2lds16(B + (size_t)(c0 + row) * HID + k0 + c8s * 8, Bl + b * 8);
    }
    __syncthreads();
    #pragma unroll
    for (int ks = 0; ks < 2; ks++) {
      bf16x8 af[2], bf[2];
      #pragma unroll
      for (int a = 0; a < 2; a++) {
        int row = wy * 32 + a * 16 + c;
        af[a] = *(const bf16x8*)(Al + row * 64 + (((4 * ks + g) ^ (row & 7)) * 8));
      }
      #pragma unroll
      for (int b = 0; b < 2; b++) {
        int row = wx * 32 + b * 16 + c;
        bf[b] = *(const bf16x8*)(Bl + row * 64 + (((4 * ks + g) ^ (row & 7)) * 8));
      }
      #pragma unroll
      for (int a = 0; a < 2; a++)
        #pragma unroll
        for (int b = 0; b < 2; b++)
          acc[a][b] = __builtin_amdgcn_mfma_f32_16x16x32_bf16(af[a], bf[b], acc[a][b], 0, 0, 0);
    }
  }
  #pragma unroll
  for (int a = 0; a < 2; a++)
    #pragma unroll
    for (int b = 0; b < 2; b++) {
      int col = c0 + wx * 32 + b * 16 + c;
      float sca = sx * SW[col];
      float bs = bias[col];
      #pragma unroll
      for (int r = 0; r < 4; r++) {
        int row = r0 + wy * 32 + a * 16 + 4 * g + r;
        C[(size_t)row * N + col] = acc[a][b][r] * sca + bs;
      }
    }
}

// generic integer-domain GEMM for the O projection
__global__ __launch_bounds__(256) void k_gemm_q(const u16* __restrict__ A, const u16* __restrict__ B,
                                                const float* __restrict__ SW, const float* __restrict__ sc,
                                                int axslot, float* __restrict__ C, int M, int N, int K) {
  __shared__ u16 Al[64 * 64];
  __shared__ u16 Bl[64 * 64];
  int tid = threadIdx.x, lane = tid & 63, w = tid >> 6;
  int g = lane >> 4, c = lane & 15;
  int wy = w >> 1, wx = w & 1;
  int r0 = blockIdx.y * 64, c0 = blockIdx.x * 64;
  float sx = mk_scale(sc[axslot]);
  f32x4 acc[2][2] = {};
  for (int k0 = 0; k0 < K; k0 += 64) {
    __syncthreads();
    #pragma unroll
    for (int i = 0; i < 2; i++) {
      int b = tid + i * 256;
      int row = b >> 3, c8d = b & 7, c8s = c8d ^ (row & 7);
      gl2lds16(A + (size_t)(r0 + row) * K + k0 + c8s * 8, Al + b * 8);
    }
    #pragma unroll
    for (int i = 0; i < 2; i++) {
      int b = tid + i * 256;
      int row = b >> 3, c8d = b & 7, c8s = c8d ^ (row & 7);
      gl2lds16(B + (size_t)(c0 + row) * K + k0 + c8s * 8, Bl + b * 8);
    }
    __syncthreads();
    #pragma unroll
    for (int ks = 0; ks < 2; ks++) {
      bf16x8 af[2], bf[2];
      #pragma unroll
      for (int a = 0; a < 2; a++) {
        int row = wy * 32 + a * 16 + c;
        af[a] = *(const bf16x8*)(Al + row * 64 + (((4 * ks + g) ^ (row & 7)) * 8));
      }
      #pragma unroll
      for (int b = 0; b < 2; b++) {
        int row = wx * 32 + b * 16 + c;
        bf[b] = *(const bf16x8*)(Bl + row * 64 + (((4 * ks + g) ^ (row & 7)) * 8));
      }
      #pragma unroll
      for (int a = 0; a < 2; a++)
        #pragma unroll
        for (int b = 0; b < 2; b++)
          acc[a][b] = __builtin_amdgcn_mfma_f32_16x16x32_bf16(af[a], bf[b], acc[a][b], 0, 0, 0);
    }
  }
  #pragma unroll
  for (int a = 0; a < 2; a++)
    #pragma unroll
    for (int b = 0; b < 2; b++) {
      int col = c0 + wx * 32 + b * 16 + c;
      float sca = sx * SW[col];
      #pragma unroll
      for (int r = 0; r < 4; r++) {
        int row = r0 + wy * 32 + a * 16 + 4 * g + r;
        C[(size_t)row * N + col] = acc[a][b][r] * sca;
      }
    }
}

// fused: RoPE(Q)+amax, RoPE(K)+amax, absmax(V). grid = 2816 blocks exactly
__global__ __launch_bounds__(256) void k_rope_amax(float* __restrict__ QB, float* __restrict__ KB,
                                                   const float* __restrict__ VB,
                                                   const float* __restrict__ cosb, const float* __restrict__ sinb,
                                                   float* __restrict__ sc) {
  const int nQ = S_LEN * NH * 64;     // 524288
  const int nK = S_LEN * NKV * 64;    // 131072
  int idx = blockIdx.x * 256 + threadIdx.x;
  float am = 0.f;
  int slotIdx;
  if (idx < nQ) {
    int s = idx >> 10, rem = idx & 1023, h = rem >> 6, d = rem & 63;
    float c1 = cosb[s * HD + d], s1 = sinb[s * HD + d];
    float c2 = cosb[s * HD + d + 64], s2 = sinb[s * HD + d + 64];
    float* p = &QB[(size_t)s * (NH * HD) + h * HD + d];
    float x1 = p[0], x2 = p[64];
    float y1 = x1 * c1 - x2 * s1;
    float y2 = x2 * c2 + x1 * s2;
    p[0] = y1; p[64] = y2;
    am = fmaxf(fabsf(y1), fabsf(y2));
    slotIdx = SC_AMAX_Q;
  } else if (idx < nQ + nK) {
    int j = idx - nQ;
    int s = j >> 8, rem = j & 255, h = rem >> 6, d = rem & 63;
    float c1 = cosb[s * HD + d], s1 = sinb[s * HD + d];
    float c2 = cosb[s * HD + d + 64], s2 = sinb[s * HD + d + 64];
    float* p = &KB[(size_t)s * (NKV * HD) + h * HD + d];
    float x1 = p[0], x2 = p[64];
    float y1 = x1 * c1 - x2 * s1;
    float y2 = x2 * c2 + x1 * s2;
    p[0] = y1; p[64] = y2;
    am = fmaxf(fabsf(y1), fabsf(y2));
    slotIdx = SC_AMAX_K;
  } else {
    int j = idx - nQ - nK;
    float4 v = ((const float4*)VB)[j];
    am = fmaxf(fmaxf(fabsf(v.x), fabsf(v.y)), fmaxf(fabsf(v.z), fabsf(v.w)));
    slotIdx = SC_AMAX_V;
  }
  am = blockMax256(am);
  if (threadIdx.x == 0) atomicMaxPosF(&sc[slotIdx], am);
}

// caches rebuilt as bf16 integer codes + kvout region appended
__global__ __launch_bounds__(256) void k_build_cache_b(const float* __restrict__ ck, const float* __restrict__ cv,
                                                       const float* __restrict__ KB, const float* __restrict__ VB,
                                                       u16* __restrict__ KCb, u16* __restrict__ VCb,
                                                       float* __restrict__ dout, const float* __restrict__ sc) {
  const int n1 = NKV * CL * HD;
  const int nko = NKV * S_LEN * HD;
  const int total = 2 * n1 + 2 * nko;
  float sck = mk_scale(sc[SC_AMAX_CK]), scv = mk_scale(sc[SC_AMAX_CV]);
  float tqk = fminf(rintf(sc[SC_AMAX_CK_TAIL] / sck), 127.f) * sck;
  float tqv = fminf(rintf(sc[SC_AMAX_CV_TAIL] / scv), 127.f) * scv;
  float skn = fmaxf(fmaxf(tqk, sc[SC_AMAX_K]), 1e-8f) / 127.f;
  float svn = fmaxf(fmaxf(tqv, sc[SC_AMAX_V]), 1e-8f) / 127.f;
  float sko = mk_scale(sc[SC_AMAX_K]), svo = mk_scale(sc[SC_AMAX_V]);
  for (int i = blockIdx.x * 256 + threadIdx.x; i < total; i += gridDim.x * 256) {
    if (i < 2 * n1) {
      int isv = i >= n1;
      int j = i - isv * n1;
      int kvh = j / (CL * HD);
      int rem = j - kvh * CL * HD;
      int t = rem / HD, d = rem - t * HD;
      float s1 = isv ? scv : sck, s2 = isv ? svn : skn;
      float outi;
      if (t < TAILN) {
        float x = (isv ? cv : ck)[(size_t)kvh * CL * HD + (size_t)(t + S_LEN) * HD + d];
        float v1 = clampq(rintf(x / s1)) * s1;
        outi = clampq(rintf(v1 / s2));
      } else {
        float x = (isv ? VB : KB)[(size_t)(t - TAILN) * (NKV * HD) + kvh * HD + d];
        outi = clampq(rintf(x / s2));
      }
      (isv ? VCb : KCb)[j] = bf16bits(outi);
    } else {
      int j = i - 2 * n1;
      int isv = j >= nko;
      int j2 = j - isv * nko;
      int kvh = j2 / (S_LEN * HD);
      int rem = j2 - kvh * S_LEN * HD;
      int s = rem / HD, d = rem - s * HD;
      float x = (isv ? VB : KB)[(size_t)s * (NKV * HD) + kvh * HD + d];
      float ss = isv ? svo : sko;
      dout[(size_t)S_LEN * HID + j] = clampq(rintf(x / ss)) * ss;
    }
  }
}

// VCb [NKV][CL][HD] -> VT [NKV][HD][CL]
__global__ __launch_bounds__(256) void k_transpose_v(const u16* __restrict__ VCb, u16* __restrict__ VT) {
  __shared__ u16 T[64][72];
  int bid = blockIdx.x;
  int kv = bid >> 8, rem = bid & 255, tb = rem >> 1, db = rem & 1;
  int tid = threadIdx.x;
  int r = tid >> 3, cb = tid & 7;
  #pragma unroll
  for (int i = 0; i < 2; i++) {
    int row = r + i * 32;
    u16x8 v = *(const u16x8*)(VCb + ((size_t)kv * CL + tb * 64 + row) * HD + db * 64 + cb * 8);
    *(u16x8*)&T[row][cb * 8] = v;
  }
  __syncthreads();
  #pragma unroll
  for (int i = 0; i < 2; i++) {
    int drow = r + i * 32;
    u16x8 v;
    #pragma unroll
    for (int j = 0; j < 8; j++) v[j] = T[cb * 8 + j][drow];
    *(u16x8*)(VT + ((size_t)kv * HD + db * 64 + drow) * CL + tb * 64 + cb * 8) = v;
  }
}

// pass 1: MFMA QK^T, batched per-tile softmax stats. grid = NH*8*KS1, XCD-chunked
__global__ __launch_bounds__(256) void k_mattn1(const u16* __restrict__ QI, const u16* __restrict__ KCb,
                                                const float* __restrict__ mask, const float* __restrict__ sc,
                                                float* __restrict__ PM, float* __restrict__ PL) {
  __shared__ u16 Kl[64 * HD];   // 16 KB
  int bid = blockIdx.x;
  int wki = (bid & 7) * (NH * 8 * KS1 / 8) + (bid >> 3);
  int kc = wki >> 7, rem2 = wki & 127, qb = rem2 >> 4, h = rem2 & 15, kv = h >> 2;
  int tid = threadIdx.x, lane = tid & 63, wv = tid >> 6, g = lane >> 4, c = lane & 15;
  float sq  = mk_scale(sc[SC_AMAX_Q]);
  float sck = mk_scale(sc[SC_AMAX_CK]);
  float tqk = fminf(rintf(sc[SC_AMAX_CK_TAIL] / sck), 127.f) * sck;
  float skn = fmaxf(fmaxf(tqk, sc[SC_AMAX_K]), 1e-8f) / 127.f;
  float sscale = sq * skn * INV_SQRT_HD;
  int q0 = qb * 64 + wv * 16;
  bf16x8 qf[4];
  {
    const u16* qrow = QI + ((size_t)h * S_LEN + q0 + c) * HD + g * 8;
    #pragma unroll
    for (int ds = 0; ds < 4; ds++) qf[ds] = *(const bf16x8*)(qrow + 32 * ds);
  }
  float m[4], l[4];
  #pragma unroll
  for (int r = 0; r < 4; r++) { m[r] = -INFINITY; l[r] = 0.f; }
  int qlane = q0 + 4 * g;
  int kbase0 = kc * KCH1;
  const u16* Kg = KCb + (size_t)kv * CL * HD;
  for (int kb = 0; kb < KCH1; kb += 64) {
    int kbase = kbase0 + kb;
    __syncthreads();
    #pragma unroll
    for (int i = 0; i < 4; i++) {
      int b = tid + i * 256;
      int row = b >> 4, c8d = b & 15, c8s = c8d ^ (row & 7);
      gl2lds16(Kg + (size_t)(kbase + row) * HD + c8s * 8, Kl + b * 8);
    }
    __syncthreads();
    f32x4 sc4[4];
    #pragma unroll
    for (int kf = 0; kf < 4; kf++) {
      f32x4 s4 = {0.f, 0.f, 0.f, 0.f};
      int krow = kf * 16 + c;
      #pragma unroll
      for (int ds = 0; ds < 4; ds++) {
        bf16x8 kf8 = *(const bf16x8*)(Kl + krow * HD + (((4 * ds + g) ^ (krow & 7)) * 8));
        s4 = __builtin_amdgcn_mfma_f32_16x16x32_bf16(qf[ds], kf8, s4, 0, 0, 0);
      }
      sc4[kf] = s4;
    }
    #pragma unroll
    for (int r = 0; r < 4; r++) {
      const float* mr = mask + (size_t)(qlane + r) * CL + kbase;
      float v0 = fmaf(sc4[0][r], sscale, mr[c]);
      float v1 = fmaf(sc4[1][r], sscale, mr[16 + c]);
      float v2 = fmaf(sc4[2][r], sscale, mr[32 + c]);
      float v3 = fmaf(sc4[3][r], sscale, mr[48 + c]);
      float tmax = fmaxf(fmaxf(v0, v1), fmaxf(v2, v3));
      float nm = fmaxf(m[r], tmax);
      float e0 = __expf(v0 - nm), e1 = __expf(v1 - nm);
      float e2 = __expf(v2 - nm), e3 = __expf(v3 - nm);
      float f = __expf(m[r] - nm);
      l[r] = fmaf(l[r], f, (e0 + e1) + (e2 + e3));
      m[r] = nm;
    }
  }
  #pragma unroll
  for (int r = 0; r < 4; r++) {
    #pragma unroll
    for (int off = 1; off < 16; off <<= 1) {
      float om = __shfl_xor(m[r], off, 64);
      float ol = __shfl_xor(l[r], off, 64);
      float nm = fmaxf(m[r], om);
      l[r] = l[r] * __expf(m[r] - nm) + ol * __expf(om - nm);
      m[r] = nm;
    }
  }
  if (c == 0) {
    size_t base = ((size_t)kc * NH + h) * S_LEN + qlane;
    #pragma unroll
    for (int r = 0; r < 4; r++) { PM[base + r] = m[r]; PL[base + r] = l[r]; }
  }
}

__global__ __launch_bounds__(256) void k_merge4(const float* __restrict__ PM, const float* __restrict__ PL,
                                                float* __restrict__ MLm, float* __restrict__ MLl, float* sc) {
  int idx = blockIdx.x * 256 + threadIdx.x;   // NH*S_LEN = 8192
  const int st = NH * S_LEN;
  float m = PM[idx];
  #pragma unroll
  for (int p = 1; p < KS1; p++) m = fmaxf(m, PM[p * st + idx]);
  float l = 0.f;
  #pragma unroll
  for (int p = 0; p < KS1; p++) l += PL[p * st + idx] * __expf(PM[p * st + idx] - m);
  MLm[idx] = m; MLl[idx] = l;
  float lm = blockMin256(l);
  if (threadIdx.x == 0) atomicMinPosF(&sc[SC_MIN_L], lm);
}

// pass 2: MFMA QK^T (bit-identical), wave-private P, MFMA PV. grid = NH*8*KS2, XCD-chunked
__global__ __launch_bounds__(256) void k_mattn2(const u16* __restrict__ QI, const u16* __restrict__ KCb,
                                                const u16* __restrict__ VT, const float* __restrict__ mask,
                                                const float* __restrict__ sc, const float* __restrict__ MLm,
                                                const float* __restrict__ MLl, float* __restrict__ AOp) {
  __shared__ u16 Kl[64 * HD];      // 16KB swizzled [key][d]
  __shared__ u16 Vl[HD * 64];      // 16KB swizzled [d][key]
  __shared__ u16 Pl[4 * 16 * 64];  // 8KB per-wave [q][key] swizzled
  int bid = blockIdx.x;
  int wki = (bid & 7) * (NH * 8 * KS2 / 8) + (bid >> 3);
  int kc = wki >> 7, rem2 = wki & 127, qb = rem2 >> 4, h = rem2 & 15, kv = h >> 2;
  int tid = threadIdx.x, lane = tid & 63, wv = tid >> 6, g = lane >> 4, c = lane & 15;
  float sq  = mk_scale(sc[SC_AMAX_Q]);
  float sck = mk_scale(sc[SC_AMAX_CK]);
  float tqk = fminf(rintf(sc[SC_AMAX_CK_TAIL] / sck), 127.f) * sck;
  float skn = fmaxf(fmaxf(tqk, sc[SC_AMAX_K]), 1e-8f) / 127.f;
  float sscale = sq * skn * INV_SQRT_HD;
  float scv = mk_scale(sc[SC_AMAX_CV]);
  float tqv = fminf(rintf(sc[SC_AMAX_CV_TAIL] / scv), 127.f) * scv;
  float svn = fmaxf(fmaxf(tqv, sc[SC_AMAX_V]), 1e-8f) / 127.f;
  float sp  = mk_scale(1.0f / sc[SC_MIN_L]);
  float rsp = 1.0f / sp;
  float psv = sp * svn;
  int q0 = qb * 64 + wv * 16;
  bf16x8 qf[4];
  {
    const u16* qrow = QI + ((size_t)h * S_LEN + q0 + c) * HD + g * 8;
    #pragma unroll
    for (int ds = 0; ds < 4; ds++) qf[ds] = *(const bf16x8*)(qrow + 32 * ds);
  }
  int qlane = q0 + 4 * g;
  float mreg[4], invl[4];
  #pragma unroll
  for (int r = 0; r < 4; r++) {
    mreg[r] = MLm[h * S_LEN + qlane + r];
    invl[r] = 1.0f / MLl[h * S_LEN + qlane + r];
  }
  f32x4 acc[8] = {};
  const u16* Kg = KCb + (size_t)kv * CL * HD;
  const u16* Vg = VT + (size_t)kv * HD * CL;
  int kbase0 = kc * KCH2;
  u16* Pw = Pl + wv * 1024;
  for (int kb = 0; kb < KCH2; kb += 64) {
    int kbase = kbase0 + kb;
    __syncthreads();
    #pragma unroll
    for (int i = 0; i < 4; i++) {     // stage K [64][128]
      int b = tid + i * 256;
      int row = b >> 4, c8d = b & 15, c8s = c8d ^ (row & 7);
      gl2lds16(Kg + (size_t)(kbase + row) * HD + c8s * 8, Kl + b * 8);
    }
    #pragma unroll
    for (int i = 0; i < 4; i++) {     // stage V^T [128][64]
      int b = tid + i * 256;
      int row = b >> 3, c8d = b & 7, c8s = c8d ^ (row & 7);
      gl2lds16(Vg + (size_t)row * CL + kbase + c8s * 8, Vl + b * 8);
    }
    __syncthreads();
    // QK^T + softmax + P quant (arithmetic identical to pass 1)
    #pragma unroll
    for (int kf = 0; kf < 4; kf++) {
      f32x4 s4 = {0.f, 0.f, 0.f, 0.f};
      int krow = kf * 16 + c;
      #pragma unroll
      for (int ds = 0; ds < 4; ds++) {
        bf16x8 kf8 = *(const bf16x8*)(Kl + krow * HD + (((4 * ds + g) ^ (krow & 7)) * 8));
        s4 = __builtin_amdgcn_mfma_f32_16x16x32_bf16(qf[ds], kf8, s4, 0, 0, 0);
      }
      int key = kbase + kf * 16 + c;
      #pragma unroll
      for (int r = 0; r < 4; r++) {
        float v = fmaf(s4[r], sscale, mask[(size_t)(qlane + r) * CL + key]);
        float p = __expf(v - mreg[r]) * invl[r];
        float pi = fminf(rintf(p * rsp), 127.f);
        int prow = 4 * g + r, pcol = kf * 16 + c;
        Pw[prow * 64 + (pcol ^ ((prow & 7) << 3))] = bf16bits(pi);
      }
    }
    // P is wave-private: wave-local wait instead of a block barrier
    asm volatile("s_waitcnt lgkmcnt(0)" ::: "memory");
    __builtin_amdgcn_sched_barrier(0);
    bf16x8 pa[2];
    #pragma unroll
    for (int s = 0; s < 2; s++)
      pa[s] = *(const bf16x8*)(Pw + c * 64 + ((32 * s + 8 * g) ^ ((c & 7) << 3)));
    #pragma unroll
    for (int dt = 0; dt < 8; dt++) {
      #pragma unroll
      for (int s = 0; s < 2; s++) {
        int drow = dt * 16 + c;
        bf16x8 vf = *(const bf16x8*)(Vl + drow * 64 + (((4 * s + g) ^ (drow & 7)) * 8));
        acc[dt] = __builtin_amdgcn_mfma_f32_16x16x32_bf16(pa[s], vf, acc[dt], 0, 0, 0);
      }
    }
  }
  float* outp = AOp + (size_t)kc * S_LEN * HID;
  #pragma unroll
  for (int dt = 0; dt < 8; dt++)
    #pragma unroll
    for (int r = 0; r < 4; r++)
      outp[(size_t)(qlane + r) * HID + h * HD + dt * 16 + c] = acc[dt][r] * psv;
}

__global__ __launch_bounds__(256) void k_combine_ao(const float* __restrict__ AOp, float* __restrict__ AO,
                                                    float* sc) {
  int idx = blockIdx.x * 256 + threadIdx.x;   // S*HID/4
  const int st = S_LEN * HID / 4;
  const f32x4* p4 = (const f32x4*)AOp;
  f32x4 a = p4[idx];
  #pragma unroll
  for (int p = 1; p < KS2; p++) {
    f32x4 b = p4[p * st + idx];
    a = a + b;
  }
  *((f32x4*)AO + idx) = a;
  float am = fmaxf(fmaxf(fabsf(a[0]), fabsf(a[1])), fmaxf(fabsf(a[2]), fabsf(a[3])));
  am = blockMax256(am);
  if (threadIdx.x == 0) atomicMaxPosF(&sc[SC_AMAX_AO], am);
}

extern "C" void kernel_launch(void* const* d_in, const int* in_sizes, int n_in,
                              void* d_out, int out_size, void* d_ws, size_t ws_size,
                              hipStream_t stream) {
  const float* hidden = (const float*)d_in[0];
  const float* cosb   = (const float*)d_in[1];
  const float* sinb   = (const float*)d_in[2];
  const float* cachek = (const float*)d_in[3];
  const float* cachev = (const float*)d_in[4];
  const float* mask   = (const float*)d_in[5];
  const float* Wq     = (const float*)d_in[6];
  const float* bq     = (const float*)d_in[7];
  const float* Wk     = (const float*)d_in[8];
  const float* bk     = (const float*)d_in[9];
  const float* Wv     = (const float*)d_in[10];
  const float* bv     = (const float*)d_in[11];
  const float* Wo     = (const float*)d_in[12];
  float* out = (float*)d_out;

  char* base = (char*)d_ws;
  auto alloc = [&](size_t bytes) { char* p = base; base += (bytes + 255) & ~(size_t)255; return p; };

  float* SC  = (float*)alloc(64 * 4);
  float* SWq = (float*)alloc(HID * 4);
  float* SWk = (float*)alloc(NKV * HD * 4);
  float* SWv = (float*)alloc(NKV * HD * 4);
  float* SWo = (float*)alloc(HID * 4);
  u16* XI    = (u16*)alloc((size_t)S_LEN * HID * 2);
  u16* WQb   = (u16*)alloc((size_t)HID * HID * 2);
  u16* WKb   = (u16*)alloc((size_t)NKV * HD * HID * 2);
  u16* WVb   = (u16*)alloc((size_t)NKV * HD * HID * 2);
  u16* WOb   = (u16*)alloc((size_t)HID * HID * 2);
  float* QB  = (float*)alloc((size_t)S_LEN * HID * 4);
  float* KB  = (float*)alloc((size_t)S_LEN * NKV * HD * 4);
  float* VB  = (float*)alloc((size_t)S_LEN * NKV * HD * 4);
  u16* KCb   = (u16*)alloc((size_t)NKV * CL * HD * 2);
  u16* VCb   = (u16*)alloc((size_t)NKV * CL * HD * 2);
  u16* VT    = (u16*)alloc((size_t)NKV * HD * CL * 2);
  u16* QI    = (u16*)alloc((size_t)NH * S_LEN * HD * 2);
  float* PM  = (float*)alloc((size_t)KS1 * NH * S_LEN * 4);
  float* PL  = (float*)alloc((size_t)KS1 * NH * S_LEN * 4);
  float* MLm = (float*)alloc((size_t)NH * S_LEN * 4);
  float* MLl = (float*)alloc((size_t)NH * S_LEN * 4);
  float* AOp = (float*)alloc((size_t)KS2 * S_LEN * HID * 4);
  float* AO  = (float*)alloc((size_t)S_LEN * HID * 4);
  u16* AOi   = (u16*)alloc((size_t)S_LEN * HID * 2);

  k_init<<<1, 64, 0, stream>>>(SC);
  k_absmax4<<<1024, 256, 0, stream>>>(hidden, S_LEN * HID / 4, &SC[SC_AMAX_X]);
  k_absmax_caches<<<2048, 256, 0, stream>>>(cachek, cachev, SC);
  k_quant_w_all<<<5120, 256, 0, stream>>>(Wq, Wk, Wv, Wo, WQb, WKb, WVb, WOb, SWq, SWk, SWv, SWo);
  k_quant_act_b<<<1024, 256, 0, stream>>>(hidden, XI, S_LEN * HID / 4, SC, SC_AMAX_X);
  {
    dim3 g(48, S_LEN / 64);
    k_gemm_qkv<<<g, 256, 0, stream>>>(XI, WQb, WKb, WVb, SWq, SWk, SWv, bq, bk, bv, SC, QB, KB, VB);
  }
  k_rope_amax<<<2816, 256, 0, stream>>>(QB, KB, VB, cosb, sinb, SC);
  k_build_cache_b<<<4096, 256, 0, stream>>>(cachek, cachev, KB, VB, KCb, VCb, out, SC);
  k_transpose_v<<<NKV * (CL / 64) * (HD / 64), 256, 0, stream>>>(VCb, VT);
  k_quant_q<<<1024, 256, 0, stream>>>(QB, QI, SC);
  k_mattn1<<<NH * 8 * KS1, 256, 0, stream>>>(QI, KCb, mask, SC, PM, PL);
  k_merge4<<<NH * S_LEN / 256, 256, 0, stream>>>(PM, PL, MLm, MLl, SC);
  k_mattn2<<<NH * 8 * KS2, 256, 0, stream>>>(QI, KCb, VT, mask, SC, MLm, MLl, AOp);
  k_combine_ao<<<1024, 256, 0, stream>>>(AOp, AO, SC);
  k_quant_act_b<<<1024, 256, 0, stream>>>(AO, AOi, S_LEN * HID / 4, SC, SC_AMAX_AO);
  {
    dim3 g(HID / 64, S_LEN / 64);
    k_gemm_q<<<g, 256, 0, stream>>>(AOi, WOb, SWo, SC, SC_AMAX_AO, out, S_LEN, HID, HID);
  }
  (void)in_sizes; (void)n_in; (void)out_size; (void)ws_size;
}

// Round 5
// 234.150 us; speedup vs baseline: 9.4022x; 1.5735x over previous
//
#include <hip/hip_runtime.h>
#include <math.h>

#define S_LEN 512
#define HID 2048
#define NH 16
#define NKV 4
#define HD 128
#define CL 8192
#define TAILN (CL - S_LEN)
#define KS1 16                 // key partitions pass 1
#define KCH1 (CL / KS1)        // 512
#define KS2 8                  // key partitions pass 2
#define KCH2 (CL / KS2)        // 1024
#define INV_SQRT_HD 0.08838834764831845f

typedef unsigned short u16;
typedef __attribute__((ext_vector_type(8))) unsigned short u16x8;
typedef __attribute__((ext_vector_type(4))) unsigned short u16x4;
typedef __attribute__((ext_vector_type(8))) short bf16x8;
typedef __attribute__((ext_vector_type(4))) float f32x4;

enum {
  SC_AMAX_X = 0, SC_AMAX_CK, SC_AMAX_CK_TAIL, SC_AMAX_CV, SC_AMAX_CV_TAIL,
  SC_AMAX_Q, SC_AMAX_K, SC_AMAX_V, SC_AMAX_AO, SC_MIN_L,
  SC_NUM
};

__device__ __forceinline__ float warpMax64(float v) {
  #pragma unroll
  for (int o = 32; o; o >>= 1) v = fmaxf(v, __shfl_down(v, o, 64));
  return v;
}
__device__ __forceinline__ float warpMin64(float v) {
  #pragma unroll
  for (int o = 32; o; o >>= 1) v = fminf(v, __shfl_down(v, o, 64));
  return v;
}
// requires blockDim.x == 256
__device__ __forceinline__ float blockMax256(float v) {
  __shared__ float sm_[4];
  __syncthreads();
  v = warpMax64(v);
  if ((threadIdx.x & 63) == 0) sm_[threadIdx.x >> 6] = v;
  __syncthreads();
  return fmaxf(fmaxf(sm_[0], sm_[1]), fmaxf(sm_[2], sm_[3]));
}
__device__ __forceinline__ float blockMin256(float v) {
  __shared__ float sn_[4];
  __syncthreads();
  v = warpMin64(v);
  if ((threadIdx.x & 63) == 0) sn_[threadIdx.x >> 6] = v;
  __syncthreads();
  return fminf(fminf(sn_[0], sn_[1]), fminf(sn_[2], sn_[3]));
}
__device__ __forceinline__ void atomicMinPosF(float* a, float v) {
  atomicMin((unsigned int*)a, __float_as_uint(v));
}
__device__ __forceinline__ float clampq(float q) {
  return fminf(fmaxf(q, -128.f), 127.f);
}
__device__ __forceinline__ u16 bf16bits(float f) {
  return (u16)(__float_as_uint(f) >> 16);   // exact for small integers
}
__device__ __forceinline__ float mk_scale(float am) {
  return fmaxf(am, 1e-8f) / 127.f;
}
__device__ __forceinline__ void gl2lds16(const u16* g, u16* l) {
  __builtin_amdgcn_global_load_lds((const __attribute__((address_space(1))) void*)g,
                                   (__attribute__((address_space(3))) void*)l, 16, 0, 0);
}

__global__ void k_init(float* sc) {
  int i = threadIdx.x;
  if (i < SC_NUM) sc[i] = (i == SC_MIN_L) ? INFINITY : 0.f;
}

// hidden absmax -> per-block partials pp[bid]. grid = 512
__global__ __launch_bounds__(256) void k_absmax_part(const float* __restrict__ x, int n4,
                                                     float* __restrict__ pp) {
  float m = 0.f;
  const float4* x4 = (const float4*)x;
  for (int i = blockIdx.x * 256 + threadIdx.x; i < n4; i += gridDim.x * 256) {
    float4 v = x4[i];
    m = fmaxf(m, fmaxf(fmaxf(fabsf(v.x), fabsf(v.y)), fmaxf(fabsf(v.z), fabsf(v.w))));
  }
  m = blockMax256(m);
  if (threadIdx.x == 0) pp[blockIdx.x] = m;
}

// both caches, full + tail partials. grid = 512; pp layout: [512+b]=ckF [1024+b]=ckT [1536+b]=cvF [2048+b]=cvT
__global__ __launch_bounds__(256) void k_absmax_caches_part(const float* __restrict__ ck,
                                                            const float* __restrict__ cv,
                                                            float* __restrict__ pp) {
  const int n4 = NKV * CL * HD / 4;
  float mkf = 0.f, mkt = 0.f, mvf = 0.f, mvt = 0.f;
  for (int i = blockIdx.x * 256 + threadIdx.x; i < 2 * n4; i += gridDim.x * 256) {
    int isv = i >= n4;
    int j = i - isv * n4;
    float4 v = ((const float4*)(isv ? cv : ck))[j];
    float a = fmaxf(fmaxf(fabsf(v.x), fabsf(v.y)), fmaxf(fabsf(v.z), fabsf(v.w)));
    int t = (j >> 5) & (CL - 1);
    if (isv) { mvf = fmaxf(mvf, a); if (t >= S_LEN) mvt = fmaxf(mvt, a); }
    else     { mkf = fmaxf(mkf, a); if (t >= S_LEN) mkt = fmaxf(mkt, a); }
  }
  mkf = blockMax256(mkf); mkt = blockMax256(mkt);
  mvf = blockMax256(mvf); mvt = blockMax256(mvt);
  if (threadIdx.x == 0) {
    pp[512 + blockIdx.x] = mkf;
    pp[1024 + blockIdx.x] = mkt;
    pp[1536 + blockIdx.x] = mvf;
    pp[2048 + blockIdx.x] = mvt;
  }
}

// single block: fold 5 ranges of 512 partials into SC slots
__global__ __launch_bounds__(256) void k_reduce_pre(const float* __restrict__ pp, float* __restrict__ sc) {
  const int slots[5] = {SC_AMAX_X, SC_AMAX_CK, SC_AMAX_CK_TAIL, SC_AMAX_CV, SC_AMAX_CV_TAIL};
  #pragma unroll
  for (int r = 0; r < 5; r++) {
    float v = fmaxf(pp[r * 512 + threadIdx.x], pp[r * 512 + 256 + threadIdx.x]);
    v = blockMax256(v);
    if (threadIdx.x == 0) sc[slots[r]] = v;
  }
}

// all 4 weight matrices, one block per output row
__global__ __launch_bounds__(256) void k_quant_w_all(const float* __restrict__ Wq, const float* __restrict__ Wk,
                                                     const float* __restrict__ Wv, const float* __restrict__ Wo,
                                                     u16* __restrict__ WQb, u16* __restrict__ WKb,
                                                     u16* __restrict__ WVb, u16* __restrict__ WOb,
                                                     float* __restrict__ SWq, float* __restrict__ SWk,
                                                     float* __restrict__ SWv, float* __restrict__ SWo) {
  int r = blockIdx.x;
  const float* W; u16* Wb; float* SW; int row;
  if (r < 2048)      { W = Wq; Wb = WQb; SW = SWq; row = r; }
  else if (r < 2560) { W = Wk; Wb = WKb; SW = SWk; row = r - 2048; }
  else if (r < 3072) { W = Wv; Wb = WVb; SW = SWv; row = r - 2560; }
  else               { W = Wo; Wb = WOb; SW = SWo; row = r - 3072; }
  size_t base = (size_t)row * HID;
  const float4* w4 = (const float4*)(W + base);
  const int n4 = HID / 4;
  float am = 0.f;
  for (int i = threadIdx.x; i < n4; i += 256) {
    float4 v = w4[i];
    am = fmaxf(am, fmaxf(fmaxf(fabsf(v.x), fabsf(v.y)), fmaxf(fabsf(v.z), fabsf(v.w))));
  }
  am = blockMax256(am);
  float s = fmaxf(am, 1e-8f) / 127.f;
  if (threadIdx.x == 0) SW[row] = s;
  for (int i = threadIdx.x; i < n4; i += 256) {
    float4 v = w4[i];
    u16x4 o;
    o[0] = bf16bits(clampq(rintf(v.x / s)));
    o[1] = bf16bits(clampq(rintf(v.y / s)));
    o[2] = bf16bits(clampq(rintf(v.z / s)));
    o[3] = bf16bits(clampq(rintf(v.w / s)));
    *(u16x4*)(Wb + base + (size_t)i * 4) = o;
  }
}

// activation fake-quant -> bf16 integer codes; scale computed inline from amax slot
__global__ __launch_bounds__(256) void k_quant_act_b(const float* __restrict__ in, u16* __restrict__ outp,
                                                     int n4, const float* __restrict__ sc, int axslot) {
  float s = mk_scale(sc[axslot]);
  const float4* i4 = (const float4*)in;
  for (int i = blockIdx.x * 256 + threadIdx.x; i < n4; i += gridDim.x * 256) {
    float4 v = i4[i];
    u16x4 o;
    o[0] = bf16bits(clampq(rintf(v.x / s)));
    o[1] = bf16bits(clampq(rintf(v.y / s)));
    o[2] = bf16bits(clampq(rintf(v.z / s)));
    o[3] = bf16bits(clampq(rintf(v.w / s)));
    *(u16x4*)(outp + (size_t)i * 4) = o;
  }
}

// QB f32 [S][NH*HD] -> QI bf16-int [NH][S][HD]
__global__ __launch_bounds__(256) void k_quant_q(const float* __restrict__ QB, u16* __restrict__ QI,
                                                 const float* __restrict__ sc) {
  int idx = blockIdx.x * 256 + threadIdx.x;
  float s = mk_scale(sc[SC_AMAX_Q]);
  int e = idx * 4;
  int srow = e >> 11, rem = e & 2047;
  int h = rem >> 7, d = rem & 127;
  float4 v = *(const float4*)&QB[e];
  u16x4 o;
  o[0] = bf16bits(clampq(rintf(v.x / s)));
  o[1] = bf16bits(clampq(rintf(v.y / s)));
  o[2] = bf16bits(clampq(rintf(v.z / s)));
  o[3] = bf16bits(clampq(rintf(v.w / s)));
  *(u16x4*)(QI + ((size_t)h * S_LEN + srow) * HD + d) = o;
}

// fused QKV GEMM: C = (XI x W^T) * (sx*SW[col]) + bias; 64x64 tiles, grid (48, 8)
__global__ __launch_bounds__(256) void k_gemm_qkv(const u16* __restrict__ A,
                                                  const u16* __restrict__ WQb, const u16* __restrict__ WKb,
                                                  const u16* __restrict__ WVb,
                                                  const float* __restrict__ SWq, const float* __restrict__ SWk,
                                                  const float* __restrict__ SWv,
                                                  const float* __restrict__ bq, const float* __restrict__ bk,
                                                  const float* __restrict__ bv,
                                                  const float* __restrict__ sc,
                                                  float* __restrict__ QB, float* __restrict__ KB,
                                                  float* __restrict__ VB) {
  __shared__ u16 Al[64 * 64];
  __shared__ u16 Bl[64 * 64];
  int bx = blockIdx.x;
  const u16* B; const float* SW; const float* bias; float* C; int N, c0;
  if (bx < 32)      { B = WQb; SW = SWq; bias = bq; C = QB; N = HID; c0 = bx * 64; }
  else if (bx < 40) { B = WKb; SW = SWk; bias = bk; C = KB; N = NKV * HD; c0 = (bx - 32) * 64; }
  else              { B = WVb; SW = SWv; bias = bv; C = VB; N = NKV * HD; c0 = (bx - 40) * 64; }
  int tid = threadIdx.x, lane = tid & 63, w = tid >> 6;
  int g = lane >> 4, c = lane & 15;
  int wy = w >> 1, wx = w & 1;
  int r0 = blockIdx.y * 64;
  float sx = mk_scale(sc[SC_AMAX_X]);
  f32x4 acc[2][2] = {};
  for (int k0 = 0; k0 < HID; k0 += 64) {
    __syncthreads();
    #pragma unroll
    for (int i = 0; i < 2; i++) {
      int b = tid + i * 256;
      int row = b >> 3, c8d = b & 7, c8s = c8d ^ (row & 7);
      gl2lds16(A + (size_t)(r0 + row) * HID + k0 + c8s * 8, Al + b * 8);
    }
    #pragma unroll
    for (int i = 0; i < 2; i++) {
      int b = tid + i * 256;
      int row = b >> 3, c8d = b & 7, c8s = c8d ^ (row & 7);
      gl2lds16(B + (size_t)(c0 + row) * HID + k0 + c8s * 8, Bl + b * 8);
    }
    __syncthreads();
    #pragma unroll
    for (int ks = 0; ks < 2; ks++) {
      bf16x8 af[2], bf[2];
      #pragma unroll
      for (int a = 0; a < 2; a++) {
        int row = wy * 32 + a * 16 + c;
        af[a] = *(const bf16x8*)(Al + row * 64 + (((4 * ks + g) ^ (row & 7)) * 8));
      }
      #pragma unroll
      for (int b = 0; b < 2; b++) {
        int row = wx * 32 + b * 16 + c;
        bf[b] = *(const bf16x8*)(Bl + row * 64 + (((4 * ks + g) ^ (row & 7)) * 8));
      }
      #pragma unroll
      for (int a = 0; a < 2; a++)
        #pragma unroll
        for (int b = 0; b < 2; b++)
          acc[a][b] = __builtin_amdgcn_mfma_f32_16x16x32_bf16(af[a], bf[b], acc[a][b], 0, 0, 0);
    }
  }
  #pragma unroll
  for (int a = 0; a < 2; a++)
    #pragma unroll
    for (int b = 0; b < 2; b++) {
      int col = c0 + wx * 32 + b * 16 + c;
      float sca = sx * SW[col];
      float bs = bias[col];
      #pragma unroll
      for (int r = 0; r < 4; r++) {
        int row = r0 + wy * 32 + a * 16 + 4 * g + r;
        C[(size_t)row * N + col] = acc[a][b][r] * sca + bs;
      }
    }
}

// generic integer-domain GEMM for the O projection
__global__ __launch_bounds__(256) void k_gemm_q(const u16* __restrict__ A, const u16* __restrict__ B,
                                                const float* __restrict__ SW, const float* __restrict__ sc,
                                                int axslot, float* __restrict__ C, int M, int N, int K) {
  __shared__ u16 Al[64 * 64];
  __shared__ u16 Bl[64 * 64];
  int tid = threadIdx.x, lane = tid & 63, w = tid >> 6;
  int g = lane >> 4, c = lane & 15;
  int wy = w >> 1, wx = w & 1;
  int r0 = blockIdx.y * 64, c0 = blockIdx.x * 64;
  float sx = mk_scale(sc[axslot]);
  f32x4 acc[2][2] = {};
  for (int k0 = 0; k0 < K; k0 += 64) {
    __syncthreads();
    #pragma unroll
    for (int i = 0; i < 2; i++) {
      int b = tid + i * 256;
      int row = b >> 3, c8d = b & 7, c8s = c8d ^ (row & 7);
      gl2lds16(A + (size_t)(r0 + row) * K + k0 + c8s * 8, Al + b * 8);
    }
    #pragma unroll
    for (int i = 0; i < 2; i++) {
      int b = tid + i * 256;
      int row = b >> 3, c8d = b & 7, c8s = c8d ^ (row & 7);
      gl2lds16(B + (size_t)(c0 + row) * K + k0 + c8s * 8, Bl + b * 8);
    }
    __syncthreads();
    #pragma unroll
    for (int ks = 0; ks < 2; ks++) {
      bf16x8 af[2], bf[2];
      #pragma unroll
      for (int a = 0; a < 2; a++) {
        int row = wy * 32 + a * 16 + c;
        af[a] = *(const bf16x8*)(Al + row * 64 + (((4 * ks + g) ^ (row & 7)) * 8));
      }
      #pragma unroll
      for (int b = 0; b < 2; b++) {
        int row = wx * 32 + b * 16 + c;
        bf[b] = *(const bf16x8*)(Bl + row * 64 + (((4 * ks + g) ^ (row & 7)) * 8));
      }
      #pragma unroll
      for (int a = 0; a < 2; a++)
        #pragma unroll
        for (int b = 0; b < 2; b++)
          acc[a][b] = __builtin_amdgcn_mfma_f32_16x16x32_bf16(af[a], bf[b], acc[a][b], 0, 0, 0);
    }
  }
  #pragma unroll
  for (int a = 0; a < 2; a++)
    #pragma unroll
    for (int b = 0; b < 2; b++) {
      int col = c0 + wx * 32 + b * 16 + c;
      float sca = sx * SW[col];
      #pragma unroll
      for (int r = 0; r < 4; r++) {
        int row = r0 + wy * 32 + a * 16 + 4 * g + r;
        C[(size_t)row * N + col] = acc[a][b][r] * sca;
      }
    }
}

// fused: RoPE(Q), RoPE(K), absmax(V) -> per-block partials PR[bid]. grid = 2816
// block ranges: [0,2048)->Q, [2048,2560)->K, [2560,2816)->V (each block fully in one segment)
__global__ __launch_bounds__(256) void k_rope_amax(float* __restrict__ QB, float* __restrict__ KB,
                                                   const float* __restrict__ VB,
                                                   const float* __restrict__ cosb, const float* __restrict__ sinb,
                                                   float* __restrict__ PR) {
  const int nQ = S_LEN * NH * 64;     // 524288
  const int nK = S_LEN * NKV * 64;    // 131072
  int idx = blockIdx.x * 256 + threadIdx.x;
  float am = 0.f;
  if (idx < nQ) {
    int s = idx >> 10, rem = idx & 1023, h = rem >> 6, d = rem & 63;
    float c1 = cosb[s * HD + d], s1 = sinb[s * HD + d];
    float c2 = cosb[s * HD + d + 64], s2 = sinb[s * HD + d + 64];
    float* p = &QB[(size_t)s * (NH * HD) + h * HD + d];
    float x1 = p[0], x2 = p[64];
    float y1 = x1 * c1 - x2 * s1;
    float y2 = x2 * c2 + x1 * s2;
    p[0] = y1; p[64] = y2;
    am = fmaxf(fabsf(y1), fabsf(y2));
  } else if (idx < nQ + nK) {
    int j = idx - nQ;
    int s = j >> 8, rem = j & 255, h = rem >> 6, d = rem & 63;
    float c1 = cosb[s * HD + d], s1 = sinb[s * HD + d];
    float c2 = cosb[s * HD + d + 64], s2 = sinb[s * HD + d + 64];
    float* p = &KB[(size_t)s * (NKV * HD) + h * HD + d];
    float x1 = p[0], x2 = p[64];
    float y1 = x1 * c1 - x2 * s1;
    float y2 = x2 * c2 + x1 * s2;
    p[0] = y1; p[64] = y2;
    am = fmaxf(fabsf(y1), fabsf(y2));
  } else {
    int j = idx - nQ - nK;
    float4 v = ((const float4*)VB)[j];
    am = fmaxf(fmaxf(fabsf(v.x), fabsf(v.y)), fmaxf(fabsf(v.z), fabsf(v.w)));
  }
  am = blockMax256(am);
  if (threadIdx.x == 0) PR[blockIdx.x] = am;
}

// single block: fold rope partials into SC_AMAX_{Q,K,V}
__global__ __launch_bounds__(256) void k_reduce_rope(const float* __restrict__ PR, float* __restrict__ sc) {
  float v = 0.f;
  #pragma unroll
  for (int i = 0; i < 8; i++) v = fmaxf(v, PR[threadIdx.x + 256 * i]);
  v = blockMax256(v);
  if (threadIdx.x == 0) sc[SC_AMAX_Q] = v;
  v = fmaxf(PR[2048 + threadIdx.x], PR[2048 + 256 + threadIdx.x]);
  v = blockMax256(v);
  if (threadIdx.x == 0) sc[SC_AMAX_K] = v;
  v = PR[2560 + threadIdx.x];
  v = blockMax256(v);
  if (threadIdx.x == 0) sc[SC_AMAX_V] = v;
}

// caches rebuilt as bf16 integer codes + kvout region appended
__global__ __launch_bounds__(256) void k_build_cache_b(const float* __restrict__ ck, const float* __restrict__ cv,
                                                       const float* __restrict__ KB, const float* __restrict__ VB,
                                                       u16* __restrict__ KCb, u16* __restrict__ VCb,
                                                       float* __restrict__ dout, const float* __restrict__ sc) {
  const int n1 = NKV * CL * HD;
  const int nko = NKV * S_LEN * HD;
  const int total = 2 * n1 + 2 * nko;
  float sck = mk_scale(sc[SC_AMAX_CK]), scv = mk_scale(sc[SC_AMAX_CV]);
  float tqk = fminf(rintf(sc[SC_AMAX_CK_TAIL] / sck), 127.f) * sck;
  float tqv = fminf(rintf(sc[SC_AMAX_CV_TAIL] / scv), 127.f) * scv;
  float skn = fmaxf(fmaxf(tqk, sc[SC_AMAX_K]), 1e-8f) / 127.f;
  float svn = fmaxf(fmaxf(tqv, sc[SC_AMAX_V]), 1e-8f) / 127.f;
  float sko = mk_scale(sc[SC_AMAX_K]), svo = mk_scale(sc[SC_AMAX_V]);
  for (int i = blockIdx.x * 256 + threadIdx.x; i < total; i += gridDim.x * 256) {
    if (i < 2 * n1) {
      int isv = i >= n1;
      int j = i - isv * n1;
      int kvh = j / (CL * HD);
      int rem = j - kvh * CL * HD;
      int t = rem / HD, d = rem - t * HD;
      float s1 = isv ? scv : sck, s2 = isv ? svn : skn;
      float outi;
      if (t < TAILN) {
        float x = (isv ? cv : ck)[(size_t)kvh * CL * HD + (size_t)(t + S_LEN) * HD + d];
        float v1 = clampq(rintf(x / s1)) * s1;
        outi = clampq(rintf(v1 / s2));
      } else {
        float x = (isv ? VB : KB)[(size_t)(t - TAILN) * (NKV * HD) + kvh * HD + d];
        outi = clampq(rintf(x / s2));
      }
      (isv ? VCb : KCb)[j] = bf16bits(outi);
    } else {
      int j = i - 2 * n1;
      int isv = j >= nko;
      int j2 = j - isv * nko;
      int kvh = j2 / (S_LEN * HD);
      int rem = j2 - kvh * S_LEN * HD;
      int s = rem / HD, d = rem - s * HD;
      float x = (isv ? VB : KB)[(size_t)s * (NKV * HD) + kvh * HD + d];
      float ss = isv ? svo : sko;
      dout[(size_t)S_LEN * HID + j] = clampq(rintf(x / ss)) * ss;
    }
  }
}

// VCb [NKV][CL][HD] -> VT [NKV][HD][CL]
__global__ __launch_bounds__(256) void k_transpose_v(const u16* __restrict__ VCb, u16* __restrict__ VT) {
  __shared__ u16 T[64][72];
  int bid = blockIdx.x;
  int kv = bid >> 8, rem = bid & 255, tb = rem >> 1, db = rem & 1;
  int tid = threadIdx.x;
  int r = tid >> 3, cb = tid & 7;
  #pragma unroll
  for (int i = 0; i < 2; i++) {
    int row = r + i * 32;
    u16x8 v = *(const u16x8*)(VCb + ((size_t)kv * CL + tb * 64 + row) * HD + db * 64 + cb * 8);
    *(u16x8*)&T[row][cb * 8] = v;
  }
  __syncthreads();
  #pragma unroll
  for (int i = 0; i < 2; i++) {
    int drow = r + i * 32;
    u16x8 v;
    #pragma unroll
    for (int j = 0; j < 8; j++) v[j] = T[cb * 8 + j][drow];
    *(u16x8*)(VT + ((size_t)kv * HD + db * 64 + drow) * CL + tb * 64 + cb * 8) = v;
  }
}

// pass 1: MFMA QK^T, batched per-tile softmax stats. grid = NH*8*KS1, XCD-chunked
__global__ __launch_bounds__(256) void k_mattn1(const u16* __restrict__ QI, const u16* __restrict__ KCb,
                                                const float* __restrict__ mask, const float* __restrict__ sc,
                                                float* __restrict__ PM, float* __restrict__ PL) {
  __shared__ u16 Kl[64 * HD];   // 16 KB
  int bid = blockIdx.x;
  int wki = (bid & 7) * (NH * 8 * KS1 / 8) + (bid >> 3);
  int kc = wki >> 7, rem2 = wki & 127, qb = rem2 >> 4, h = rem2 & 15, kv = h >> 2;
  int tid = threadIdx.x, lane = tid & 63, wv = tid >> 6, g = lane >> 4, c = lane & 15;
  float sq  = mk_scale(sc[SC_AMAX_Q]);
  float sck = mk_scale(sc[SC_AMAX_CK]);
  float tqk = fminf(rintf(sc[SC_AMAX_CK_TAIL] / sck), 127.f) * sck;
  float skn = fmaxf(fmaxf(tqk, sc[SC_AMAX_K]), 1e-8f) / 127.f;
  float sscale = sq * skn * INV_SQRT_HD;
  int q0 = qb * 64 + wv * 16;
  bf16x8 qf[4];
  {
    const u16* qrow = QI + ((size_t)h * S_LEN + q0 + c) * HD + g * 8;
    #pragma unroll
    for (int ds = 0; ds < 4; ds++) qf[ds] = *(const bf16x8*)(qrow + 32 * ds);
  }
  float m[4], l[4];
  #pragma unroll
  for (int r = 0; r < 4; r++) { m[r] = -INFINITY; l[r] = 0.f; }
  int qlane = q0 + 4 * g;
  int kbase0 = kc * KCH1;
  const u16* Kg = KCb + (size_t)kv * CL * HD;
  for (int kb = 0; kb < KCH1; kb += 64) {
    int kbase = kbase0 + kb;
    __syncthreads();
    #pragma unroll
    for (int i = 0; i < 4; i++) {
      int b = tid + i * 256;
      int row = b >> 4, c8d = b & 15, c8s = c8d ^ (row & 7);
      gl2lds16(Kg + (size_t)(kbase + row) * HD + c8s * 8, Kl + b * 8);
    }
    __syncthreads();
    f32x4 sc4[4];
    #pragma unroll
    for (int kf = 0; kf < 4; kf++) {
      f32x4 s4 = {0.f, 0.f, 0.f, 0.f};
      int krow = kf * 16 + c;
      #pragma unroll
      for (int ds = 0; ds < 4; ds++) {
        bf16x8 kf8 = *(const bf16x8*)(Kl + krow * HD + (((4 * ds + g) ^ (krow & 7)) * 8));
        s4 = __builtin_amdgcn_mfma_f32_16x16x32_bf16(qf[ds], kf8, s4, 0, 0, 0);
      }
      sc4[kf] = s4;
    }
    #pragma unroll
    for (int r = 0; r < 4; r++) {
      const float* mr = mask + (size_t)(qlane + r) * CL + kbase;
      float v0 = fmaf(sc4[0][r], sscale, mr[c]);
      float v1 = fmaf(sc4[1][r], sscale, mr[16 + c]);
      float v2 = fmaf(sc4[2][r], sscale, mr[32 + c]);
      float v3 = fmaf(sc4[3][r], sscale, mr[48 + c]);
      float tmax = fmaxf(fmaxf(v0, v1), fmaxf(v2, v3));
      float nm = fmaxf(m[r], tmax);
      float e0 = __expf(v0 - nm), e1 = __expf(v1 - nm);
      float e2 = __expf(v2 - nm), e3 = __expf(v3 - nm);
      float f = __expf(m[r] - nm);
      l[r] = fmaf(l[r], f, (e0 + e1) + (e2 + e3));
      m[r] = nm;
    }
  }
  #pragma unroll
  for (int r = 0; r < 4; r++) {
    #pragma unroll
    for (int off = 1; off < 16; off <<= 1) {
      float om = __shfl_xor(m[r], off, 64);
      float ol = __shfl_xor(l[r], off, 64);
      float nm = fmaxf(m[r], om);
      l[r] = l[r] * __expf(m[r] - nm) + ol * __expf(om - nm);
      m[r] = nm;
    }
  }
  if (c == 0) {
    size_t base = ((size_t)kc * NH + h) * S_LEN + qlane;
    #pragma unroll
    for (int r = 0; r < 4; r++) { PM[base + r] = m[r]; PL[base + r] = l[r]; }
  }
}

__global__ __launch_bounds__(256) void k_merge4(const float* __restrict__ PM, const float* __restrict__ PL,
                                                float* __restrict__ MLm, float* __restrict__ MLl, float* sc) {
  int idx = blockIdx.x * 256 + threadIdx.x;   // NH*S_LEN = 8192
  const int st = NH * S_LEN;
  float m = PM[idx];
  #pragma unroll
  for (int p = 1; p < KS1; p++) m = fmaxf(m, PM[p * st + idx]);
  float l = 0.f;
  #pragma unroll
  for (int p = 0; p < KS1; p++) l += PL[p * st + idx] * __expf(PM[p * st + idx] - m);
  MLm[idx] = m; MLl[idx] = l;
  float lm = blockMin256(l);
  if (threadIdx.x == 0) atomicMinPosF(&sc[SC_MIN_L], lm);
}

// pass 2: MFMA QK^T (bit-identical), wave-private P, MFMA PV. grid = NH*8*KS2, XCD-chunked
__global__ __launch_bounds__(256) void k_mattn2(const u16* __restrict__ QI, const u16* __restrict__ KCb,
                                                const u16* __restrict__ VT, const float* __restrict__ mask,
                                                const float* __restrict__ sc, const float* __restrict__ MLm,
                                                const float* __restrict__ MLl, float* __restrict__ AOp) {
  __shared__ u16 Kl[64 * HD];      // 16KB swizzled [key][d]
  __shared__ u16 Vl[HD * 64];      // 16KB swizzled [d][key]
  __shared__ u16 Pl[4 * 16 * 64];  // 8KB per-wave [q][key] swizzled
  int bid = blockIdx.x;
  int wki = (bid & 7) * (NH * 8 * KS2 / 8) + (bid >> 3);
  int kc = wki >> 7, rem2 = wki & 127, qb = rem2 >> 4, h = rem2 & 15, kv = h >> 2;
  int tid = threadIdx.x, lane = tid & 63, wv = tid >> 6, g = lane >> 4, c = lane & 15;
  float sq  = mk_scale(sc[SC_AMAX_Q]);
  float sck = mk_scale(sc[SC_AMAX_CK]);
  float tqk = fminf(rintf(sc[SC_AMAX_CK_TAIL] / sck), 127.f) * sck;
  float skn = fmaxf(fmaxf(tqk, sc[SC_AMAX_K]), 1e-8f) / 127.f;
  float sscale = sq * skn * INV_SQRT_HD;
  float scv = mk_scale(sc[SC_AMAX_CV]);
  float tqv = fminf(rintf(sc[SC_AMAX_CV_TAIL] / scv), 127.f) * scv;
  float svn = fmaxf(fmaxf(tqv, sc[SC_AMAX_V]), 1e-8f) / 127.f;
  float sp  = mk_scale(1.0f / sc[SC_MIN_L]);
  float rsp = 1.0f / sp;
  float psv = sp * svn;
  int q0 = qb * 64 + wv * 16;
  bf16x8 qf[4];
  {
    const u16* qrow = QI + ((size_t)h * S_LEN + q0 + c) * HD + g * 8;
    #pragma unroll
    for (int ds = 0; ds < 4; ds++) qf[ds] = *(const bf16x8*)(qrow + 32 * ds);
  }
  int qlane = q0 + 4 * g;
  float mreg[4], invl[4];
  #pragma unroll
  for (int r = 0; r < 4; r++) {
    mreg[r] = MLm[h * S_LEN + qlane + r];
    invl[r] = 1.0f / MLl[h * S_LEN + qlane + r];
  }
  f32x4 acc[8] = {};
  const u16* Kg = KCb + (size_t)kv * CL * HD;
  const u16* Vg = VT + (size_t)kv * HD * CL;
  int kbase0 = kc * KCH2;
  u16* Pw = Pl + wv * 1024;
  for (int kb = 0; kb < KCH2; kb += 64) {
    int kbase = kbase0 + kb;
    __syncthreads();
    #pragma unroll
    for (int i = 0; i < 4; i++) {     // stage K [64][128]
      int b = tid + i * 256;
      int row = b >> 4, c8d = b & 15, c8s = c8d ^ (row & 7);
      gl2lds16(Kg + (size_t)(kbase + row) * HD + c8s * 8, Kl + b * 8);
    }
    #pragma unroll
    for (int i = 0; i < 4; i++) {     // stage V^T [128][64]
      int b = tid + i * 256;
      int row = b >> 3, c8d = b & 7, c8s = c8d ^ (row & 7);
      gl2lds16(Vg + (size_t)row * CL + kbase + c8s * 8, Vl + b * 8);
    }
    __syncthreads();
    // QK^T + softmax + P quant (arithmetic identical to pass 1)
    #pragma unroll
    for (int kf = 0; kf < 4; kf++) {
      f32x4 s4 = {0.f, 0.f, 0.f, 0.f};
      int krow = kf * 16 + c;
      #pragma unroll
      for (int ds = 0; ds < 4; ds++) {
        bf16x8 kf8 = *(const bf16x8*)(Kl + krow * HD + (((4 * ds + g) ^ (krow & 7)) * 8));
        s4 = __builtin_amdgcn_mfma_f32_16x16x32_bf16(qf[ds], kf8, s4, 0, 0, 0);
      }
      int key = kbase + kf * 16 + c;
      #pragma unroll
      for (int r = 0; r < 4; r++) {
        float v = fmaf(s4[r], sscale, mask[(size_t)(qlane + r) * CL + key]);
        float p = __expf(v - mreg[r]) * invl[r];
        float pi = fminf(rintf(p * rsp), 127.f);
        int prow = 4 * g + r, pcol = kf * 16 + c;
        Pw[prow * 64 + (pcol ^ ((prow & 7) << 3))] = bf16bits(pi);
      }
    }
    // P is wave-private: wave-local wait instead of a block barrier
    asm volatile("s_waitcnt lgkmcnt(0)" ::: "memory");
    __builtin_amdgcn_sched_barrier(0);
    bf16x8 pa[2];
    #pragma unroll
    for (int s = 0; s < 2; s++)
      pa[s] = *(const bf16x8*)(Pw + c * 64 + ((32 * s + 8 * g) ^ ((c & 7) << 3)));
    #pragma unroll
    for (int dt = 0; dt < 8; dt++) {
      #pragma unroll
      for (int s = 0; s < 2; s++) {
        int drow = dt * 16 + c;
        bf16x8 vf = *(const bf16x8*)(Vl + drow * 64 + (((4 * s + g) ^ (drow & 7)) * 8));
        acc[dt] = __builtin_amdgcn_mfma_f32_16x16x32_bf16(pa[s], vf, acc[dt], 0, 0, 0);
      }
    }
  }
  float* outp = AOp + (size_t)kc * S_LEN * HID;
  #pragma unroll
  for (int dt = 0; dt < 8; dt++)
    #pragma unroll
    for (int r = 0; r < 4; r++)
      outp[(size_t)(qlane + r) * HID + h * HD + dt * 16 + c] = acc[dt][r] * psv;
}

__global__ __launch_bounds__(256) void k_combine_ao(const float* __restrict__ AOp, float* __restrict__ AO,
                                                    float* __restrict__ PA) {
  int idx = blockIdx.x * 256 + threadIdx.x;   // S*HID/4
  const int st = S_LEN * HID / 4;
  const f32x4* p4 = (const f32x4*)AOp;
  f32x4 a = p4[idx];
  #pragma unroll
  for (int p = 1; p < KS2; p++) {
    f32x4 b = p4[p * st + idx];
    a = a + b;
  }
  *((f32x4*)AO + idx) = a;
  float am = fmaxf(fmaxf(fabsf(a[0]), fabsf(a[1])), fmaxf(fabsf(a[2]), fabsf(a[3])));
  am = blockMax256(am);
  if (threadIdx.x == 0) PA[blockIdx.x] = am;
}

// single block: fold AO partials into SC_AMAX_AO
__global__ __launch_bounds__(256) void k_reduce_ao(const float* __restrict__ PA, float* __restrict__ sc) {
  float v = 0.f;
  #pragma unroll
  for (int i = 0; i < 4; i++) v = fmaxf(v, PA[threadIdx.x + 256 * i]);
  v = blockMax256(v);
  if (threadIdx.x == 0) sc[SC_AMAX_AO] = v;
}

extern "C" void kernel_launch(void* const* d_in, const int* in_sizes, int n_in,
                              void* d_out, int out_size, void* d_ws, size_t ws_size,
                              hipStream_t stream) {
  const float* hidden = (const float*)d_in[0];
  const float* cosb   = (const float*)d_in[1];
  const float* sinb   = (const float*)d_in[2];
  const float* cachek = (const float*)d_in[3];
  const float* cachev = (const float*)d_in[4];
  const float* mask   = (const float*)d_in[5];
  const float* Wq     = (const float*)d_in[6];
  const float* bq     = (const float*)d_in[7];
  const float* Wk     = (const float*)d_in[8];
  const float* bk     = (const float*)d_in[9];
  const float* Wv     = (const float*)d_in[10];
  const float* bv     = (const float*)d_in[11];
  const float* Wo     = (const float*)d_in[12];
  float* out = (float*)d_out;

  char* base = (char*)d_ws;
  auto alloc = [&](size_t bytes) { char* p = base; base += (bytes + 255) & ~(size_t)255; return p; };

  float* SC  = (float*)alloc(64 * 4);
  float* PP  = (float*)alloc(2560 * 4);
  float* PR  = (float*)alloc(2816 * 4);
  float* PA  = (float*)alloc(1024 * 4);
  float* SWq = (float*)alloc(HID * 4);
  float* SWk = (float*)alloc(NKV * HD * 4);
  float* SWv = (float*)alloc(NKV * HD * 4);
  float* SWo = (float*)alloc(HID * 4);
  u16* XI    = (u16*)alloc((size_t)S_LEN * HID * 2);
  u16* WQb   = (u16*)alloc((size_t)HID * HID * 2);
  u16* WKb   = (u16*)alloc((size_t)NKV * HD * HID * 2);
  u16* WVb   = (u16*)alloc((size_t)NKV * HD * HID * 2);
  u16* WOb   = (u16*)alloc((size_t)HID * HID * 2);
  float* QB  = (float*)alloc((size_t)S_LEN * HID * 4);
  float* KB  = (float*)alloc((size_t)S_LEN * NKV * HD * 4);
  float* VB  = (float*)alloc((size_t)S_LEN * NKV * HD * 4);
  u16* KCb   = (u16*)alloc((size_t)NKV * CL * HD * 2);
  u16* VCb   = (u16*)alloc((size_t)NKV * CL * HD * 2);
  u16* VT    = (u16*)alloc((size_t)NKV * HD * CL * 2);
  u16* QI    = (u16*)alloc((size_t)NH * S_LEN * HD * 2);
  float* PM  = (float*)alloc((size_t)KS1 * NH * S_LEN * 4);
  float* PL  = (float*)alloc((size_t)KS1 * NH * S_LEN * 4);
  float* MLm = (float*)alloc((size_t)NH * S_LEN * 4);
  float* MLl = (float*)alloc((size_t)NH * S_LEN * 4);
  float* AOp = (float*)alloc((size_t)KS2 * S_LEN * HID * 4);
  float* AO  = (float*)alloc((size_t)S_LEN * HID * 4);
  u16* AOi   = (u16*)alloc((size_t)S_LEN * HID * 2);

  k_init<<<1, 64, 0, stream>>>(SC);
  k_absmax_part<<<512, 256, 0, stream>>>(hidden, S_LEN * HID / 4, PP);
  k_absmax_caches_part<<<512, 256, 0, stream>>>(cachek, cachev, PP);
  k_reduce_pre<<<1, 256, 0, stream>>>(PP, SC);
  k_quant_w_all<<<5120, 256, 0, stream>>>(Wq, Wk, Wv, Wo, WQb, WKb, WVb, WOb, SWq, SWk, SWv, SWo);
  k_quant_act_b<<<1024, 256, 0, stream>>>(hidden, XI, S_LEN * HID / 4, SC, SC_AMAX_X);
  {
    dim3 g(48, S_LEN / 64);
    k_gemm_qkv<<<g, 256, 0, stream>>>(XI, WQb, WKb, WVb, SWq, SWk, SWv, bq, bk, bv, SC, QB, KB, VB);
  }
  k_rope_amax<<<2816, 256, 0, stream>>>(QB, KB, VB, cosb, sinb, PR);
  k_reduce_rope<<<1, 256, 0, stream>>>(PR, SC);
  k_build_cache_b<<<4096, 256, 0, stream>>>(cachek, cachev, KB, VB, KCb, VCb, out, SC);
  k_transpose_v<<<NKV * (CL / 64) * (HD / 64), 256, 0, stream>>>(VCb, VT);
  k_quant_q<<<1024, 256, 0, stream>>>(QB, QI, SC);
  k_mattn1<<<NH * 8 * KS1, 256, 0, stream>>>(QI, KCb, mask, SC, PM, PL);
  k_merge4<<<NH * S_LEN / 256, 256, 0, stream>>>(PM, PL, MLm, MLl, SC);
  k_mattn2<<<NH * 8 * KS2, 256, 0, stream>>>(QI, KCb, VT, mask, SC, MLm, MLl, AOp);
  k_combine_ao<<<1024, 256, 0, stream>>>(AOp, AO, PA);
  k_reduce_ao<<<1, 256, 0, stream>>>(PA, SC);
  k_quant_act_b<<<1024, 256, 0, stream>>>(AO, AOi, S_LEN * HID / 4, SC, SC_AMAX_AO);
  {
    dim3 g(HID / 64, S_LEN / 64);
    k_gemm_q<<<g, 256, 0, stream>>>(AOi, WOb, SWo, SC, SC_AMAX_AO, out, S_LEN, HID, HID);
  }
  (void)in_sizes; (void)n_in; (void)out_size; (void)ws_size;
}